// Round 1
// baseline (1018.660 us; speedup 1.0000x reference)
//
#include <hip/hip_runtime.h>
#include <math.h>

#define NB 8
#define LL 512
#define EE 128
#define HD 256
#define QD 512
#define IND 512
#define NHEAD 4
#define NTYPE 3
#define FHD 64
#define LHID 128
#define G4 512

__device__ __forceinline__ float sigm(float x){ return 1.f/(1.f+expf(-x)); }

// ---------------- K1: entity max/mean pooling ----------------
__global__ void k_ent_state(const float* __restrict__ doc, const float* __restrict__ emap,
                            float* __restrict__ ES){
  int ne = blockIdx.x;            // n*128+e
  int n = ne >> 7;
  int tid = threadIdx.x;          // 256 threads = d
  __shared__ float mrow_s[512];
  for (int l = tid; l < 512; l += 256) mrow_s[l] = emap[(size_t)ne*512 + l];
  __syncthreads();
  const float* dbase = doc + (size_t)n*512*256 + tid;
  float sum = 0.f, mx = -3.402823e38f, msum = 0.f;
  int cnt = 0;
  for (int l = 0; l < 512; l++){
    float m = mrow_s[l];
    if (m != 0.f){                // uniform branch across block
      float v = m * dbase[(size_t)l*256];
      sum += v; mx = fmaxf(mx, v); msum += m; cnt++;
    }
  }
  if (cnt < 512) mx = fmaxf(mx, 0.f);
  float elen = (msum == 0.f) ? 1.f : msum;
  float* o = ES + (size_t)ne*512;
  o[tid] = mx;
  o[256 + tid] = sum / elen;
}

// ---------------- K2: query = query_vec @ query_weight ----------------
__global__ void k_query(const float* __restrict__ qv, const float* __restrict__ qw,
                        float* __restrict__ Q){
  int n = blockIdx.x; int tid = threadIdx.x;    // 512
  __shared__ float q[512];
  q[tid] = qv[n*512 + tid];
  __syncthreads();
  float acc = 0.f;
  for (int k = 0; k < 512; k++) acc += q[k] * qw[(size_t)k*512 + tid];
  Q[n*512 + tid] = acc;
}

// ---------------- K3: query scores, softmask, adj_mask ----------------
__global__ void k_qscore(const float* __restrict__ ES, const float* __restrict__ Q,
                         const float* __restrict__ emask, float* __restrict__ sm_out,
                         float* __restrict__ AM){
  int n = blockIdx.x; int e = threadIdx.x;      // 128
  __shared__ float q[512];
  for (int k = e; k < 512; k += 128) q[k] = Q[n*512 + k];
  __syncthreads();
  const float* es = ES + ((size_t)(n*128 + e))*512;
  float acc = 0.f;
  for (int k = 0; k < 512; k++) acc += es[k] * q[k];
  float s = (acc * (1.f/512.f)) * emask[n*128 + e];
  sm_out[n*128 + e] = s;
  AM[n*128 + e] = sigm(s);
}

// ---------------- K4: h_all = ES @ W_type  (12 x [1024x512x64]) ----------------
__global__ void k_hall(const float* __restrict__ ES, const float* __restrict__ Wt,
                       float* __restrict__ HALL){
  int net = blockIdx.x;   // 16 tiles of 64 ne-rows
  int ht  = blockIdx.y;   // 12
  int tid = threadIdx.x;  // 256
  int ty = tid >> 4, tx = tid & 15;
  __shared__ float As[64][65];
  __shared__ float Bs[64][65];
  int ne0 = net*64;
  float acc[4][4] = {};
  for (int k0 = 0; k0 < 512; k0 += 64){
    for (int idx = tid; idx < 4096; idx += 256){
      int r = idx >> 6, k = idx & 63;
      As[r][k] = ES[(size_t)(ne0 + r)*512 + k0 + k];
    }
    for (int idx = tid; idx < 4096; idx += 256){
      int k = idx >> 6, f = idx & 63;
      Bs[k][f] = Wt[((size_t)ht*512 + k0 + k)*64 + f];
    }
    __syncthreads();
    #pragma unroll 16
    for (int k = 0; k < 64; k++){
      float a0 = As[ty*4+0][k], a1 = As[ty*4+1][k], a2 = As[ty*4+2][k], a3 = As[ty*4+3][k];
      float b0 = Bs[k][tx*4+0], b1 = Bs[k][tx*4+1], b2 = Bs[k][tx*4+2], b3 = Bs[k][tx*4+3];
      acc[0][0]+=a0*b0; acc[0][1]+=a0*b1; acc[0][2]+=a0*b2; acc[0][3]+=a0*b3;
      acc[1][0]+=a1*b0; acc[1][1]+=a1*b1; acc[1][2]+=a1*b2; acc[1][3]+=a1*b3;
      acc[2][0]+=a2*b0; acc[2][1]+=a2*b1; acc[2][2]+=a2*b2; acc[2][3]+=a2*b3;
      acc[3][0]+=a3*b0; acc[3][1]+=a3*b1; acc[3][2]+=a3*b2; acc[3][3]+=a3*b3;
    }
    __syncthreads();
  }
  for (int ri = 0; ri < 4; ri++)
    for (int ci = 0; ci < 4; ci++)
      HALL[((size_t)ht*1024 + ne0 + ty*4 + ri)*64 + tx*4 + ci] = acc[ri][ci];
}

// ---------------- K5: qattn gates -> WSRC/WDST ----------------
__global__ void k_qattn(const float* __restrict__ qv, const float* __restrict__ W1,
                        const float* __restrict__ W2, const float* __restrict__ at,
                        float* __restrict__ WSRC, float* __restrict__ WDST){
  int ht = blockIdx.x;    // 12
  int f = threadIdx.x;    // 128
  __shared__ float qv_s[8][512];
  __shared__ float qg1[8][128];
  for (int idx = f; idx < 4096; idx += 128) qv_s[idx >> 9][idx & 511] = qv[idx];
  __syncthreads();
  const float* w1 = W1 + (size_t)ht*512*128;
  const float* w2 = W2 + (size_t)ht*128*128;
  float acc[8] = {};
  for (int k = 0; k < 512; k++){
    float wv = w1[(size_t)k*128 + f];
    #pragma unroll
    for (int n = 0; n < 8; n++) acc[n] += qv_s[n][k] * wv;
  }
  #pragma unroll
  for (int n = 0; n < 8; n++) qg1[n][f] = fmaxf(acc[n], 0.f);
  __syncthreads();
  float acc2[8] = {};
  for (int g = 0; g < 128; g++){
    float wv = w2[(size_t)g*128 + f];
    #pragma unroll
    for (int n = 0; n < 8; n++) acc2[n] += qg1[n][g] * wv;
  }
  float av = at[ht*128 + f];
  #pragma unroll
  for (int n = 0; n < 8; n++){
    float coef = sigm(acc2[n]) * av;
    if (f < 64) WSRC[(ht*8 + n)*64 + f] = coef;
    else        WDST[(ht*8 + n)*64 + f - 64] = coef;
  }
}

// ---------------- K6: src/dst projections ----------------
__global__ void k_srcdst(const float* __restrict__ HALL, const float* __restrict__ WSRC,
                         const float* __restrict__ WDST, float* __restrict__ SRC,
                         float* __restrict__ DST){
  int b = blockIdx.x;     // ht*8+n, 96
  int e = threadIdx.x;    // 128
  __shared__ float w1[64], w2[64];
  if (e < 64) w1[e] = WSRC[b*64 + e]; else w2[e-64] = WDST[b*64 + e - 64];
  __syncthreads();
  int ht = b >> 3, n = b & 7;
  const float* h = HALL + ((size_t)ht*1024 + n*128 + e)*64;
  float s = 0.f, d = 0.f;
  #pragma unroll 8
  for (int f = 0; f < 64; f++){ float hv = h[f]; s += hv*w1[f]; d += hv*w2[f]; }
  SRC[b*128 + e] = s; DST[b*128 + e] = d;
}

// ---------------- K7: typed scores -> softmax -> heads -> entity_state2 ----------------
__global__ void k_attn(const float* __restrict__ HALL, const float* __restrict__ SRC,
                       const float* __restrict__ DST, const float* __restrict__ AM,
                       const int* __restrict__ adj, float* __restrict__ ES2,
                       float* __restrict__ out_ent){
  int b = blockIdx.x;                  // 256 = h(4) x n(8) x chunk(8)
  int h = b >> 6, n = (b >> 3) & 7, chunk = b & 7;
  int i0 = chunk*16;
  int tid = threadIdx.x;               // 128
  __shared__ float dst_l[3][128];
  __shared__ float src_l[3][16];
  __shared__ float hl[128][65];
  __shared__ float coef_l[128];
  __shared__ float redbuf[2];
  for (int idx = tid; idx < 384; idx += 128){
    int t = idx >> 7, j = idx & 127;
    dst_l[t][j] = DST[((h*3 + t)*8 + n)*128 + j];
  }
  if (tid < 48){
    int t = tid >> 4, r = tid & 15;
    src_l[t][r] = SRC[((h*3 + t)*8 + n)*128 + i0 + r];
  }
  for (int idx = tid; idx < 8192; idx += 128){
    int j = idx >> 6, f = idx & 63;
    hl[j][f] = HALL[((size_t)(h*3 + 2)*1024 + n*128 + j)*64 + f] * AM[n*128 + j];
  }
  __syncthreads();
  const int* arow = adj + (size_t)n*128*128;
  for (int r = 0; r < 16; r++){
    int i = i0 + r;
    int a = arow[(size_t)i*128 + tid];
    float s;
    if (a > 0){
      float v = src_l[a-1][r] + dst_l[a-1][tid];
      s = v > 0.f ? v : 0.2f*v;
    } else s = -1e30f;
    float m = s;
    #pragma unroll
    for (int o = 32; o > 0; o >>= 1) m = fmaxf(m, __shfl_xor(m, o, 64));
    int w = tid >> 6;
    if ((tid & 63) == 0) redbuf[w] = m;
    __syncthreads();
    float mx = fmaxf(redbuf[0], redbuf[1]);
    float p = expf(s - mx);
    float ps = p;
    #pragma unroll
    for (int o = 32; o > 0; o >>= 1) ps += __shfl_xor(ps, o, 64);
    __syncthreads();
    if ((tid & 63) == 0) redbuf[w] = ps;
    __syncthreads();
    float denom = redbuf[0] + redbuf[1];
    coef_l[tid] = p / denom;
    __syncthreads();
    if (tid < 64){
      float acc = 0.f;
      for (int j = 0; j < 128; j++) acc += coef_l[j] * hl[j][tid];
      float v = fmaxf(acc, 0.f);
      size_t oidx = ((size_t)n*128 + i)*256 + h*64 + tid;
      ES2[oidx] = v;
      out_ent[oidx] = v;
    }
    __syncthreads();
  }
}

// ---------------- K8: expand entities back to tokens, build LSTM input ----------------
__global__ void k_expand(const float* __restrict__ ES2, const float* __restrict__ emap,
                         const float* __restrict__ doc, float* __restrict__ INP){
  int b = blockIdx.x;       // n*512+l, 4096
  int n = b >> 9, l = b & 511;
  int tid = threadIdx.x;    // 256
  __shared__ float mcol[128];
  if (tid < 128) mcol[tid] = emap[((size_t)n*128 + tid)*512 + l];
  __syncthreads();
  float acc = 0.f;
  const float* e2 = ES2 + (size_t)n*128*256 + tid;
  for (int e = 0; e < 128; e++){
    float m = mcol[e];
    if (m != 0.f) acc += m * e2[(size_t)e*256];   // uniform branch
  }
  float* o = INP + (size_t)b*512;
  o[tid] = acc;
  o[256 + tid] = doc[(size_t)b*256 + tid];
}

// ---------------- K9: input-projection GEMMs (both dirs), bias folded ----------------
__global__ void k_gatein(const float* __restrict__ INP, const float* __restrict__ Wf,
                         const float* __restrict__ Wb, const float* __restrict__ bihf,
                         const float* __restrict__ bhhf, const float* __restrict__ bihb,
                         const float* __restrict__ bhhb, float* __restrict__ GF,
                         float* __restrict__ GB){
  int mt = blockIdx.x, gt = blockIdx.y, dir = blockIdx.z;
  const float* W = dir ? Wb : Wf;
  float* Gout = dir ? GB : GF;
  const float* bi = dir ? bihb : bihf;
  const float* bh = dir ? bhhb : bhhf;
  int tid = threadIdx.x;   // 256
  int ty = tid >> 4, tx = tid & 15;
  __shared__ float As[64][65];
  __shared__ float Bs[64][65];
  int m0 = mt*64, g0 = gt*64;
  float acc[4][4] = {};
  for (int k0 = 0; k0 < 512; k0 += 64){
    for (int idx = tid; idx < 4096; idx += 256){
      int r = idx >> 6, k = idx & 63;
      As[r][k] = INP[(size_t)(m0 + r)*512 + k0 + k];
    }
    for (int idx = tid; idx < 4096; idx += 256){
      int c = idx >> 6, k = idx & 63;
      Bs[k][c] = W[(size_t)(g0 + c)*512 + k0 + k];
    }
    __syncthreads();
    #pragma unroll 16
    for (int k = 0; k < 64; k++){
      float a0 = As[ty*4+0][k], a1 = As[ty*4+1][k], a2 = As[ty*4+2][k], a3 = As[ty*4+3][k];
      float b0 = Bs[k][tx*4+0], b1 = Bs[k][tx*4+1], b2 = Bs[k][tx*4+2], b3 = Bs[k][tx*4+3];
      acc[0][0]+=a0*b0; acc[0][1]+=a0*b1; acc[0][2]+=a0*b2; acc[0][3]+=a0*b3;
      acc[1][0]+=a1*b0; acc[1][1]+=a1*b1; acc[1][2]+=a1*b2; acc[1][3]+=a1*b3;
      acc[2][0]+=a2*b0; acc[2][1]+=a2*b1; acc[2][2]+=a2*b2; acc[2][3]+=a2*b3;
      acc[3][0]+=a3*b0; acc[3][1]+=a3*b1; acc[3][2]+=a3*b2; acc[3][3]+=a3*b3;
    }
    __syncthreads();
  }
  for (int ri = 0; ri < 4; ri++)
    for (int ci = 0; ci < 4; ci++){
      int g = g0 + tx*4 + ci;
      Gout[(size_t)(m0 + ty*4 + ri)*512 + g] = acc[ri][ci] + bi[g] + bh[g];
    }
}

// ---------------- K10: LSTM recurrence, 16 blocks (n x dir) ----------------
__global__ __launch_bounds__(1024) void k_lstm(const float* __restrict__ GF,
                                               const float* __restrict__ GB,
                                               const float* __restrict__ Whhf,
                                               const float* __restrict__ Whhb,
                                               float* __restrict__ out){
  int b = blockIdx.x;          // 16
  int dir = b >> 3, n = b & 7;
  const float* G = dir ? GB : GF;
  const float* Whh = dir ? Whhb : Whhf;
  int tid = threadIdx.x;       // 1024
  int g = tid & 511, half = tid >> 9;
  float w[64];
  #pragma unroll
  for (int k = 0; k < 64; k++) w[k] = Whh[(size_t)g*128 + half*64 + k];
  __shared__ __align__(16) float h_l[128];
  __shared__ float part[2][512];
  if (tid < 128) h_l[tid] = 0.f;
  float c = 0.f;
  float g0v=0.f, g1v=0.f, g2v=0.f, g3v=0.f;
  {
    int tt0 = dir ? 511 : 0;
    if (tid < 128){
      const float* Gr = G + ((size_t)(n*512 + tt0))*512;
      g0v = Gr[tid]; g1v = Gr[128+tid]; g2v = Gr[256+tid]; g3v = Gr[384+tid];
    }
  }
  __syncthreads();
  for (int t = 0; t < 512; t++){
    int tt = dir ? (511 - t) : t;
    const float4* hp = (const float4*)(h_l + half*64);
    float acc = 0.f;
    #pragma unroll
    for (int k4 = 0; k4 < 16; k4++){
      float4 hv = hp[k4];
      acc += w[k4*4+0]*hv.x + w[k4*4+1]*hv.y + w[k4*4+2]*hv.z + w[k4*4+3]*hv.w;
    }
    part[half][g] = acc;
    __syncthreads();
    if (tid < 128){
      float iv = g0v + part[0][tid]       + part[1][tid];
      float fv = g1v + part[0][128+tid]   + part[1][128+tid];
      float gv = g2v + part[0][256+tid]   + part[1][256+tid];
      float ov = g3v + part[0][384+tid]   + part[1][384+tid];
      float is = sigm(iv), fs = sigm(fv);
      float gt = tanhf(gv), os = sigm(ov);
      c = fs*c + is*gt;
      float hv = os * tanhf(c);
      h_l[tid] = hv;
      out[((size_t)(n*512 + tt))*256 + dir*128 + tid] = hv;
      if (t < 511){
        int tn = dir ? (511 - (t+1)) : (t+1);
        const float* Gr = G + ((size_t)(n*512 + tn))*512;
        g0v = Gr[tid]; g1v = Gr[128+tid]; g2v = Gr[256+tid]; g3v = Gr[384+tid];
      }
    }
    __syncthreads();
  }
}

extern "C" void kernel_launch(void* const* d_in, const int* in_sizes, int n_in,
                              void* d_out, int out_size, void* d_ws, size_t ws_size,
                              hipStream_t stream){
  const float* doc   = (const float*)d_in[0];
  const float* qvec  = (const float*)d_in[1];
  const float* emap  = (const float*)d_in[3];
  const float* emask = (const float*)d_in[4];
  const float* qw    = (const float*)d_in[5];
  const float* Wt    = (const float*)d_in[6];
  const float* at    = (const float*)d_in[7];
  const float* qa1   = (const float*)d_in[8];
  const float* qa2   = (const float*)d_in[9];
  const float* Wihf  = (const float*)d_in[10];
  const float* Whhf  = (const float*)d_in[11];
  const float* bihf  = (const float*)d_in[12];
  const float* bhhf  = (const float*)d_in[13];
  const float* Wihb  = (const float*)d_in[14];
  const float* Whhb  = (const float*)d_in[15];
  const float* bihb  = (const float*)d_in[16];
  const float* bhhb  = (const float*)d_in[17];
  const int*   adj   = (const int*)d_in[19];

  float* out = (float*)d_out;
  float* out_doc = out;                         // 8*512*256
  float* out_ent = out + 8*512*256;             // 8*128*256
  float* out_sm  = out_ent + 8*128*256;         // 8*128

  float* w = (float*)d_ws;
  float* ES   = w; w += 8*128*512;
  float* QRY  = w; w += 8*512;
  float* AM   = w; w += 8*128;
  float* HALL = w; w += 12*1024*64;
  float* WSRC = w; w += 12*8*64;
  float* WDST = w; w += 12*8*64;
  float* SRC  = w; w += 12*8*128;
  float* DST  = w; w += 12*8*128;
  float* ES2  = w; w += 8*128*256;
  float* INP  = w; w += 8*512*512;
  float* GF   = w; w += 8*512*512;
  float* GB   = w; w += 8*512*512;

  hipLaunchKernelGGL(k_ent_state, dim3(1024), dim3(256), 0, stream, doc, emap, ES);
  hipLaunchKernelGGL(k_query,     dim3(8),    dim3(512), 0, stream, qvec, qw, QRY);
  hipLaunchKernelGGL(k_qscore,    dim3(8),    dim3(128), 0, stream, ES, QRY, emask, out_sm, AM);
  hipLaunchKernelGGL(k_hall,      dim3(16,12),dim3(256), 0, stream, ES, Wt, HALL);
  hipLaunchKernelGGL(k_qattn,     dim3(12),   dim3(128), 0, stream, qvec, qa1, qa2, at, WSRC, WDST);
  hipLaunchKernelGGL(k_srcdst,    dim3(96),   dim3(128), 0, stream, HALL, WSRC, WDST, SRC, DST);
  hipLaunchKernelGGL(k_attn,      dim3(256),  dim3(128), 0, stream, HALL, SRC, DST, AM, adj, ES2, out_ent);
  hipLaunchKernelGGL(k_expand,    dim3(4096), dim3(256), 0, stream, ES2, emap, doc, INP);
  hipLaunchKernelGGL(k_gatein,    dim3(64,8,2), dim3(256), 0, stream, INP, Wihf, Wihb, bihf, bhhf, bihb, bhhb, GF, GB);
  hipLaunchKernelGGL(k_lstm,      dim3(16),   dim3(1024), 0, stream, GF, GB, Whhf, Whhb, out_doc);
}

// Round 2
// 748.530 us; speedup vs baseline: 1.3609x; 1.3609x over previous
//
#include <hip/hip_runtime.h>
#include <math.h>

typedef _Float16 h2 __attribute__((ext_vector_type(2)));

__device__ __forceinline__ float sigm(float x){ return 1.f/(1.f+expf(-x)); }

__device__ __forceinline__ float fsigm(float x){
  float e = __expf(-x);
  return __builtin_amdgcn_rcpf(1.f + e);
}
__device__ __forceinline__ float ftanh(float x){
  float xx = fminf(fmaxf(x, -15.f), 15.f);
  float e = __expf(2.f * xx);
  return 1.f - 2.f * __builtin_amdgcn_rcpf(e + 1.f);
}
__device__ __forceinline__ h2 u2h(unsigned u){
  union { unsigned u; h2 h; } x; x.u = u; return x.h;
}
__device__ __forceinline__ float fdot2(h2 a, h2 b, float c){
#if __has_builtin(__builtin_amdgcn_fdot2)
  return __builtin_amdgcn_fdot2(a, b, c, false);
#else
  return c + (float)a[0]*(float)b[0] + (float)a[1]*(float)b[1];
#endif
}

// ---------------- K1: entity max/mean pooling ----------------
__global__ void k_ent_state(const float* __restrict__ doc, const float* __restrict__ emap,
                            float* __restrict__ ES){
  int ne = blockIdx.x;            // n*128+e
  int n = ne >> 7;
  int tid = threadIdx.x;          // 256 threads = d
  __shared__ float mrow_s[512];
  for (int l = tid; l < 512; l += 256) mrow_s[l] = emap[(size_t)ne*512 + l];
  __syncthreads();
  const float* dbase = doc + (size_t)n*512*256 + tid;
  float sum = 0.f, mx = -3.402823e38f, msum = 0.f;
  int cnt = 0;
  for (int l = 0; l < 512; l++){
    float m = mrow_s[l];
    if (m != 0.f){                // uniform branch across block
      float v = m * dbase[(size_t)l*256];
      sum += v; mx = fmaxf(mx, v); msum += m; cnt++;
    }
  }
  if (cnt < 512) mx = fmaxf(mx, 0.f);
  float elen = (msum == 0.f) ? 1.f : msum;
  float* o = ES + (size_t)ne*512;
  o[tid] = mx;
  o[256 + tid] = sum / elen;
}

// ---------------- K2: query = query_vec @ query_weight ----------------
__global__ void k_query(const float* __restrict__ qv, const float* __restrict__ qw,
                        float* __restrict__ Q){
  int n = blockIdx.x; int tid = threadIdx.x;    // 512
  __shared__ float q[512];
  q[tid] = qv[n*512 + tid];
  __syncthreads();
  float acc = 0.f;
  for (int k = 0; k < 512; k++) acc += q[k] * qw[(size_t)k*512 + tid];
  Q[n*512 + tid] = acc;
}

// ---------------- K3: query scores, softmask, adj_mask ----------------
__global__ void k_qscore(const float* __restrict__ ES, const float* __restrict__ Q,
                         const float* __restrict__ emask, float* __restrict__ sm_out,
                         float* __restrict__ AM){
  int n = blockIdx.x; int e = threadIdx.x;      // 128
  __shared__ float q[512];
  for (int k = e; k < 512; k += 128) q[k] = Q[n*512 + k];
  __syncthreads();
  const float* es = ES + ((size_t)(n*128 + e))*512;
  float acc = 0.f;
  for (int k = 0; k < 512; k++) acc += es[k] * q[k];
  float s = (acc * (1.f/512.f)) * emask[n*128 + e];
  sm_out[n*128 + e] = s;
  AM[n*128 + e] = sigm(s);
}

// ---------------- K4: h_all = ES @ W_type  (12 x [1024x512x64]) ----------------
__global__ void k_hall(const float* __restrict__ ES, const float* __restrict__ Wt,
                       float* __restrict__ HALL){
  int net = blockIdx.x;   // 16 tiles of 64 ne-rows
  int ht  = blockIdx.y;   // 12
  int tid = threadIdx.x;  // 256
  int ty = tid >> 4, tx = tid & 15;
  __shared__ float As[64][65];
  __shared__ float Bs[64][65];
  int ne0 = net*64;
  float acc[4][4] = {};
  for (int k0 = 0; k0 < 512; k0 += 64){
    for (int idx = tid; idx < 4096; idx += 256){
      int r = idx >> 6, k = idx & 63;
      As[r][k] = ES[(size_t)(ne0 + r)*512 + k0 + k];
    }
    for (int idx = tid; idx < 4096; idx += 256){
      int k = idx >> 6, f = idx & 63;
      Bs[k][f] = Wt[((size_t)ht*512 + k0 + k)*64 + f];
    }
    __syncthreads();
    #pragma unroll 16
    for (int k = 0; k < 64; k++){
      float a0 = As[ty*4+0][k], a1 = As[ty*4+1][k], a2 = As[ty*4+2][k], a3 = As[ty*4+3][k];
      float b0 = Bs[k][tx*4+0], b1 = Bs[k][tx*4+1], b2 = Bs[k][tx*4+2], b3 = Bs[k][tx*4+3];
      acc[0][0]+=a0*b0; acc[0][1]+=a0*b1; acc[0][2]+=a0*b2; acc[0][3]+=a0*b3;
      acc[1][0]+=a1*b0; acc[1][1]+=a1*b1; acc[1][2]+=a1*b2; acc[1][3]+=a1*b3;
      acc[2][0]+=a2*b0; acc[2][1]+=a2*b1; acc[2][2]+=a2*b2; acc[2][3]+=a2*b3;
      acc[3][0]+=a3*b0; acc[3][1]+=a3*b1; acc[3][2]+=a3*b2; acc[3][3]+=a3*b3;
    }
    __syncthreads();
  }
  for (int ri = 0; ri < 4; ri++)
    for (int ci = 0; ci < 4; ci++)
      HALL[((size_t)ht*1024 + ne0 + ty*4 + ri)*64 + tx*4 + ci] = acc[ri][ci];
}

// ---------------- K5: qattn gates -> WSRC/WDST ----------------
__global__ void k_qattn(const float* __restrict__ qv, const float* __restrict__ W1,
                        const float* __restrict__ W2, const float* __restrict__ at,
                        float* __restrict__ WSRC, float* __restrict__ WDST){
  int ht = blockIdx.x;    // 12
  int f = threadIdx.x;    // 128
  __shared__ float qv_s[8][512];
  __shared__ float qg1[8][128];
  for (int idx = f; idx < 4096; idx += 128) qv_s[idx >> 9][idx & 511] = qv[idx];
  __syncthreads();
  const float* w1 = W1 + (size_t)ht*512*128;
  const float* w2 = W2 + (size_t)ht*128*128;
  float acc[8] = {};
  for (int k = 0; k < 512; k++){
    float wv = w1[(size_t)k*128 + f];
    #pragma unroll
    for (int n = 0; n < 8; n++) acc[n] += qv_s[n][k] * wv;
  }
  #pragma unroll
  for (int n = 0; n < 8; n++) qg1[n][f] = fmaxf(acc[n], 0.f);
  __syncthreads();
  float acc2[8] = {};
  for (int g = 0; g < 128; g++){
    float wv = w2[(size_t)g*128 + f];
    #pragma unroll
    for (int n = 0; n < 8; n++) acc2[n] += qg1[n][g] * wv;
  }
  float av = at[ht*128 + f];
  #pragma unroll
  for (int n = 0; n < 8; n++){
    float coef = sigm(acc2[n]) * av;
    if (f < 64) WSRC[(ht*8 + n)*64 + f] = coef;
    else        WDST[(ht*8 + n)*64 + f - 64] = coef;
  }
}

// ---------------- K6: src/dst projections ----------------
__global__ void k_srcdst(const float* __restrict__ HALL, const float* __restrict__ WSRC,
                         const float* __restrict__ WDST, float* __restrict__ SRC,
                         float* __restrict__ DST){
  int b = blockIdx.x;     // ht*8+n, 96
  int e = threadIdx.x;    // 128
  __shared__ float w1[64], w2[64];
  if (e < 64) w1[e] = WSRC[b*64 + e]; else w2[e-64] = WDST[b*64 + e - 64];
  __syncthreads();
  int ht = b >> 3, n = b & 7;
  const float* h = HALL + ((size_t)ht*1024 + n*128 + e)*64;
  float s = 0.f, d = 0.f;
  #pragma unroll 8
  for (int f = 0; f < 64; f++){ float hv = h[f]; s += hv*w1[f]; d += hv*w2[f]; }
  SRC[b*128 + e] = s; DST[b*128 + e] = d;
}

// ---------------- K7: typed scores -> softmax -> heads -> entity_state2 ----------------
__global__ void k_attn(const float* __restrict__ HALL, const float* __restrict__ SRC,
                       const float* __restrict__ DST, const float* __restrict__ AM,
                       const int* __restrict__ adj, float* __restrict__ ES2,
                       float* __restrict__ out_ent){
  int b = blockIdx.x;                  // 256 = h(4) x n(8) x chunk(8)
  int h = b >> 6, n = (b >> 3) & 7, chunk = b & 7;
  int i0 = chunk*16;
  int tid = threadIdx.x;               // 128
  __shared__ float dst_l[3][128];
  __shared__ float src_l[3][16];
  __shared__ float hl[128][65];
  __shared__ float coef_l[128];
  __shared__ float redbuf[2];
  for (int idx = tid; idx < 384; idx += 128){
    int t = idx >> 7, j = idx & 127;
    dst_l[t][j] = DST[((h*3 + t)*8 + n)*128 + j];
  }
  if (tid < 48){
    int t = tid >> 4, r = tid & 15;
    src_l[t][r] = SRC[((h*3 + t)*8 + n)*128 + i0 + r];
  }
  for (int idx = tid; idx < 8192; idx += 128){
    int j = idx >> 6, f = idx & 63;
    hl[j][f] = HALL[((size_t)(h*3 + 2)*1024 + n*128 + j)*64 + f] * AM[n*128 + j];
  }
  __syncthreads();
  const int* arow = adj + (size_t)n*128*128;
  for (int r = 0; r < 16; r++){
    int i = i0 + r;
    int a = arow[(size_t)i*128 + tid];
    float s;
    if (a > 0){
      float v = src_l[a-1][r] + dst_l[a-1][tid];
      s = v > 0.f ? v : 0.2f*v;
    } else s = -1e30f;
    float m = s;
    #pragma unroll
    for (int o = 32; o > 0; o >>= 1) m = fmaxf(m, __shfl_xor(m, o, 64));
    int w = tid >> 6;
    if ((tid & 63) == 0) redbuf[w] = m;
    __syncthreads();
    float mx = fmaxf(redbuf[0], redbuf[1]);
    float p = expf(s - mx);
    float ps = p;
    #pragma unroll
    for (int o = 32; o > 0; o >>= 1) ps += __shfl_xor(ps, o, 64);
    __syncthreads();
    if ((tid & 63) == 0) redbuf[w] = ps;
    __syncthreads();
    float denom = redbuf[0] + redbuf[1];
    coef_l[tid] = p / denom;
    __syncthreads();
    if (tid < 64){
      float acc = 0.f;
      for (int j = 0; j < 128; j++) acc += coef_l[j] * hl[j][tid];
      float v = fmaxf(acc, 0.f);
      size_t oidx = ((size_t)n*128 + i)*256 + h*64 + tid;
      ES2[oidx] = v;
      out_ent[oidx] = v;
    }
    __syncthreads();
  }
}

// ---------------- K8: expand entities back to tokens, build LSTM input ----------------
__global__ void k_expand(const float* __restrict__ ES2, const float* __restrict__ emap,
                         const float* __restrict__ doc, float* __restrict__ INP){
  int b = blockIdx.x;       // n*512+l, 4096
  int n = b >> 9, l = b & 511;
  int tid = threadIdx.x;    // 256
  __shared__ float mcol[128];
  if (tid < 128) mcol[tid] = emap[((size_t)n*128 + tid)*512 + l];
  __syncthreads();
  float acc = 0.f;
  const float* e2 = ES2 + (size_t)n*128*256 + tid;
  for (int e = 0; e < 128; e++){
    float m = mcol[e];
    if (m != 0.f) acc += m * e2[(size_t)e*256];   // uniform branch
  }
  float* o = INP + (size_t)b*512;
  o[tid] = acc;
  o[256 + tid] = doc[(size_t)b*256 + tid];
}

// ---------------- K9: input-projection GEMMs (both dirs), bias folded ----------------
__global__ void k_gatein(const float* __restrict__ INP, const float* __restrict__ Wf,
                         const float* __restrict__ Wb, const float* __restrict__ bihf,
                         const float* __restrict__ bhhf, const float* __restrict__ bihb,
                         const float* __restrict__ bhhb, float* __restrict__ GF,
                         float* __restrict__ GB){
  int mt = blockIdx.x, gt = blockIdx.y, dir = blockIdx.z;
  const float* W = dir ? Wb : Wf;
  float* Gout = dir ? GB : GF;
  const float* bi = dir ? bihb : bihf;
  const float* bh = dir ? bhhb : bhhf;
  int tid = threadIdx.x;   // 256
  int ty = tid >> 4, tx = tid & 15;
  __shared__ float As[64][65];
  __shared__ float Bs[64][65];
  int m0 = mt*64, g0 = gt*64;
  float acc[4][4] = {};
  for (int k0 = 0; k0 < 512; k0 += 64){
    for (int idx = tid; idx < 4096; idx += 256){
      int r = idx >> 6, k = idx & 63;
      As[r][k] = INP[(size_t)(m0 + r)*512 + k0 + k];
    }
    for (int idx = tid; idx < 4096; idx += 256){
      int c = idx >> 6, k = idx & 63;
      Bs[k][c] = W[(size_t)(g0 + c)*512 + k0 + k];
    }
    __syncthreads();
    #pragma unroll 16
    for (int k = 0; k < 64; k++){
      float a0 = As[ty*4+0][k], a1 = As[ty*4+1][k], a2 = As[ty*4+2][k], a3 = As[ty*4+3][k];
      float b0 = Bs[k][tx*4+0], b1 = Bs[k][tx*4+1], b2 = Bs[k][tx*4+2], b3 = Bs[k][tx*4+3];
      acc[0][0]+=a0*b0; acc[0][1]+=a0*b1; acc[0][2]+=a0*b2; acc[0][3]+=a0*b3;
      acc[1][0]+=a1*b0; acc[1][1]+=a1*b1; acc[1][2]+=a1*b2; acc[1][3]+=a1*b3;
      acc[2][0]+=a2*b0; acc[2][1]+=a2*b1; acc[2][2]+=a2*b2; acc[2][3]+=a2*b3;
      acc[3][0]+=a3*b0; acc[3][1]+=a3*b1; acc[3][2]+=a3*b2; acc[3][3]+=a3*b3;
    }
    __syncthreads();
  }
  for (int ri = 0; ri < 4; ri++)
    for (int ci = 0; ci < 4; ci++){
      int g = g0 + tx*4 + ci;
      Gout[(size_t)(m0 + ty*4 + ri)*512 + g] = acc[ri][ci] + bi[g] + bh[g];
    }
}

// ---------------- K10: LSTM recurrence ----------------
// 16 blocks (n x dir) x 512 threads (8 waves). Wave w owns 16 hidden units;
// lane layout: j = w*16 + (lane&15), gate q = lane>>4. Whh row in registers
// as packed f16 (64 VGPRs); h double-buffered in LDS as f16; gate exchange
// via intra-wave shfl_xor (no 2nd barrier); G prefetched 2 steps ahead.
__global__ __launch_bounds__(512) void k_lstm(const float* __restrict__ GF,
                                              const float* __restrict__ GB,
                                              const float* __restrict__ Whhf,
                                              const float* __restrict__ Whhb,
                                              float* __restrict__ out){
  int b = blockIdx.x;          // 16
  int dir = b >> 3, n = b & 7;
  const float* G = dir ? GB : GF;
  const float* Whh = dir ? Whhb : Whhf;
  int tid = threadIdx.x;       // 512
  int lane = tid & 63, w = tid >> 6;
  int j = w*16 + (lane & 15);
  int q = lane >> 4;
  int row = q*128 + j;

  // pack Whh row into 64 f16x2 registers
  h2 wreg[64];
  #pragma unroll
  for (int kk = 0; kk < 64; kk++){
    float w0 = Whh[(size_t)row*128 + 2*kk];
    float w1 = Whh[(size_t)row*128 + 2*kk + 1];
    h2 p; p[0] = (_Float16)w0; p[1] = (_Float16)w1;
    wreg[kk] = p;
  }

  __shared__ __align__(16) _Float16 h_l[2][128];
  if (tid < 128){ h_l[0][tid] = (_Float16)0.f; }

  const float* Gbase = G + (size_t)n*512*512 + q*128 + j;
  // G row index for step t
  auto gidx = [&](int t)->size_t {
    int tt = dir ? (511 - t) : t;
    return (size_t)tt * 512;
  };
  float gA = Gbase[gidx(0)];
  float gB = Gbase[gidx(1)];
  float c = 0.f;

  bool q0 = (q == 0), q1 = (q == 1), q2 = (q == 2), q3 = (q == 3);
  float* outbase = out + (size_t)n*512*256 + dir*128 + j;

  __syncthreads();

  for (int t = 0; t < 512; t++){
    int rb = t & 1, wb = rb ^ 1;
    float gcur = gA;
    gA = gB;
    if (t + 2 < 512) gB = Gbase[gidx(t + 2)];

    // MV: pre = Whh[row,:] . h  (+ gate input)
    const uint4* hb = (const uint4*)(&h_l[rb][0]);
    uint4 hv[16];
    #pragma unroll
    for (int r = 0; r < 16; r++) hv[r] = hb[r];
    float a0 = 0.f, a1 = 0.f, a2 = 0.f, a3 = 0.f;
    #pragma unroll
    for (int r = 0; r < 16; r++){
      a0 = fdot2(wreg[4*r+0], u2h(hv[r].x), a0);
      a1 = fdot2(wreg[4*r+1], u2h(hv[r].y), a1);
      a2 = fdot2(wreg[4*r+2], u2h(hv[r].z), a2);
      a3 = fdot2(wreg[4*r+3], u2h(hv[r].w), a3);
    }
    float pre = (a0 + a1) + (a2 + a3) + gcur;

    // intra-wave exchange of the 4 gate pre-acts for unit j
    float s16 = __shfl_xor(pre, 16, 64);
    float s32 = __shfl_xor(pre, 32, 64);
    float s48 = __shfl_xor(pre, 48, 64);
    float vi = q0 ? pre : (q1 ? s16 : (q2 ? s32 : s48));
    float vf = q1 ? pre : (q0 ? s16 : (q2 ? s48 : s32));
    float vg = q2 ? pre : (q3 ? s16 : (q0 ? s32 : s48));
    float vo = q3 ? pre : (q2 ? s16 : (q1 ? s32 : s48));

    c = fsigm(vf) * c + fsigm(vi) * ftanh(vg);
    float hval = fsigm(vo) * ftanh(c);

    if (q0){
      h_l[wb][j] = (_Float16)hval;
      int tt = dir ? (511 - t) : t;
      outbase[(size_t)tt * 256] = hval;
    }
    __syncthreads();
  }
}

extern "C" void kernel_launch(void* const* d_in, const int* in_sizes, int n_in,
                              void* d_out, int out_size, void* d_ws, size_t ws_size,
                              hipStream_t stream){
  const float* doc   = (const float*)d_in[0];
  const float* qvec  = (const float*)d_in[1];
  const float* emap  = (const float*)d_in[3];
  const float* emask = (const float*)d_in[4];
  const float* qw    = (const float*)d_in[5];
  const float* Wt    = (const float*)d_in[6];
  const float* at    = (const float*)d_in[7];
  const float* qa1   = (const float*)d_in[8];
  const float* qa2   = (const float*)d_in[9];
  const float* Wihf  = (const float*)d_in[10];
  const float* Whhf  = (const float*)d_in[11];
  const float* bihf  = (const float*)d_in[12];
  const float* bhhf  = (const float*)d_in[13];
  const float* Wihb  = (const float*)d_in[14];
  const float* Whhb  = (const float*)d_in[15];
  const float* bihb  = (const float*)d_in[16];
  const float* bhhb  = (const float*)d_in[17];
  const int*   adj   = (const int*)d_in[19];

  float* out = (float*)d_out;
  float* out_doc = out;                         // 8*512*256
  float* out_ent = out + 8*512*256;             // 8*128*256
  float* out_sm  = out_ent + 8*128*256;         // 8*128

  float* w = (float*)d_ws;
  float* ES   = w; w += 8*128*512;
  float* QRY  = w; w += 8*512;
  float* AM   = w; w += 8*128;
  float* HALL = w; w += 12*1024*64;
  float* WSRC = w; w += 12*8*64;
  float* WDST = w; w += 12*8*64;
  float* SRC  = w; w += 12*8*128;
  float* DST  = w; w += 12*8*128;
  float* ES2  = w; w += 8*128*256;
  float* INP  = w; w += 8*512*512;
  float* GF   = w; w += 8*512*512;
  float* GB   = w; w += 8*512*512;

  hipLaunchKernelGGL(k_ent_state, dim3(1024), dim3(256), 0, stream, doc, emap, ES);
  hipLaunchKernelGGL(k_query,     dim3(8),    dim3(512), 0, stream, qvec, qw, QRY);
  hipLaunchKernelGGL(k_qscore,    dim3(8),    dim3(128), 0, stream, ES, QRY, emask, out_sm, AM);
  hipLaunchKernelGGL(k_hall,      dim3(16,12),dim3(256), 0, stream, ES, Wt, HALL);
  hipLaunchKernelGGL(k_qattn,     dim3(12),   dim3(128), 0, stream, qvec, qa1, qa2, at, WSRC, WDST);
  hipLaunchKernelGGL(k_srcdst,    dim3(96),   dim3(128), 0, stream, HALL, WSRC, WDST, SRC, DST);
  hipLaunchKernelGGL(k_attn,      dim3(256),  dim3(128), 0, stream, HALL, SRC, DST, AM, adj, ES2, out_ent);
  hipLaunchKernelGGL(k_expand,    dim3(4096), dim3(256), 0, stream, ES2, emap, doc, INP);
  hipLaunchKernelGGL(k_gatein,    dim3(64,8,2), dim3(256), 0, stream, INP, Wihf, Wihb, bihf, bhhf, bihb, bhhb, GF, GB);
  hipLaunchKernelGGL(k_lstm,      dim3(16),   dim3(512), 0, stream, GF, GB, Whhf, Whhb, out_doc);
}

// Round 3
// 601.914 us; speedup vs baseline: 1.6924x; 1.2436x over previous
//
#include <hip/hip_runtime.h>
#include <math.h>

typedef _Float16 h2 __attribute__((ext_vector_type(2)));

__device__ __forceinline__ float sigm(float x){ return 1.f/(1.f+expf(-x)); }

__device__ __forceinline__ float fsigm(float x){
  float e = __expf(-x);
  return __builtin_amdgcn_rcpf(1.f + e);
}
__device__ __forceinline__ float ftanh(float x){
  float xx = fminf(fmaxf(x, -15.f), 15.f);
  float e = __expf(2.f * xx);
  return 1.f - 2.f * __builtin_amdgcn_rcpf(e + 1.f);
}
__device__ __forceinline__ h2 u2h(unsigned u){
  union { unsigned u; h2 h; } x; x.u = u; return x.h;
}
__device__ __forceinline__ float fdot2(h2 a, h2 b, float c){
#if __has_builtin(__builtin_amdgcn_fdot2)
  return __builtin_amdgcn_fdot2(a, b, c, false);
#else
  return c + (float)a[0]*(float)b[0] + (float)a[1]*(float)b[1];
#endif
}
// quad_perm DPP helper (VALU cross-lane, no DS pipe)
template<int CTRL>
__device__ __forceinline__ float qperm(float v){
  return __int_as_float(__builtin_amdgcn_mov_dpp(__float_as_int(v), CTRL, 0xf, 0xf, true));
}

// ---------------- K1: entity max/mean pooling ----------------
__global__ void k_ent_state(const float* __restrict__ doc, const float* __restrict__ emap,
                            float* __restrict__ ES){
  int ne = blockIdx.x;            // n*128+e
  int n = ne >> 7;
  int tid = threadIdx.x;          // 256 threads = d
  __shared__ float mrow_s[512];
  for (int l = tid; l < 512; l += 256) mrow_s[l] = emap[(size_t)ne*512 + l];
  __syncthreads();
  const float* dbase = doc + (size_t)n*512*256 + tid;
  float sum = 0.f, mx = -3.402823e38f, msum = 0.f;
  int cnt = 0;
  for (int l = 0; l < 512; l++){
    float m = mrow_s[l];
    if (m != 0.f){                // uniform branch across block
      float v = m * dbase[(size_t)l*256];
      sum += v; mx = fmaxf(mx, v); msum += m; cnt++;
    }
  }
  if (cnt < 512) mx = fmaxf(mx, 0.f);
  float elen = (msum == 0.f) ? 1.f : msum;
  float* o = ES + (size_t)ne*512;
  o[tid] = mx;
  o[256 + tid] = sum / elen;
}

// ---------------- K2: query = query_vec @ query_weight ----------------
__global__ void k_query(const float* __restrict__ qv, const float* __restrict__ qw,
                        float* __restrict__ Q){
  int n = blockIdx.x; int tid = threadIdx.x;    // 512
  __shared__ float q[512];
  q[tid] = qv[n*512 + tid];
  __syncthreads();
  float acc = 0.f;
  for (int k = 0; k < 512; k++) acc += q[k] * qw[(size_t)k*512 + tid];
  Q[n*512 + tid] = acc;
}

// ---------------- K3: query scores, softmask, adj_mask ----------------
__global__ void k_qscore(const float* __restrict__ ES, const float* __restrict__ Q,
                         const float* __restrict__ emask, float* __restrict__ sm_out,
                         float* __restrict__ AM){
  int n = blockIdx.x; int e = threadIdx.x;      // 128
  __shared__ float q[512];
  for (int k = e; k < 512; k += 128) q[k] = Q[n*512 + k];
  __syncthreads();
  const float* es = ES + ((size_t)(n*128 + e))*512;
  float acc = 0.f;
  for (int k = 0; k < 512; k++) acc += es[k] * q[k];
  float s = (acc * (1.f/512.f)) * emask[n*128 + e];
  sm_out[n*128 + e] = s;
  AM[n*128 + e] = sigm(s);
}

// ---------------- K4: h_all = ES @ W_type  (12 x [1024x512x64]) ----------------
__global__ void k_hall(const float* __restrict__ ES, const float* __restrict__ Wt,
                       float* __restrict__ HALL){
  int net = blockIdx.x;   // 16 tiles of 64 ne-rows
  int ht  = blockIdx.y;   // 12
  int tid = threadIdx.x;  // 256
  int ty = tid >> 4, tx = tid & 15;
  __shared__ float As[64][68];
  __shared__ float Bs[64][68];
  int ne0 = net*64;
  float acc[4][4] = {};
  for (int k0 = 0; k0 < 512; k0 += 64){
    for (int idx = tid; idx < 4096; idx += 256){
      int r = idx >> 6, k = idx & 63;
      As[r][k] = ES[(size_t)(ne0 + r)*512 + k0 + k];
    }
    for (int idx = tid; idx < 4096; idx += 256){
      int k = idx >> 6, f = idx & 63;
      Bs[k][f] = Wt[((size_t)ht*512 + k0 + k)*64 + f];
    }
    __syncthreads();
    const float4* A0 = (const float4*)&As[ty*4+0][0];
    const float4* A1 = (const float4*)&As[ty*4+1][0];
    const float4* A2 = (const float4*)&As[ty*4+2][0];
    const float4* A3 = (const float4*)&As[ty*4+3][0];
    #pragma unroll
    for (int k4 = 0; k4 < 16; k4++){
      float4 av[4] = {A0[k4], A1[k4], A2[k4], A3[k4]};
      float4 bv[4] = {*(const float4*)&Bs[4*k4+0][tx*4], *(const float4*)&Bs[4*k4+1][tx*4],
                      *(const float4*)&Bs[4*k4+2][tx*4], *(const float4*)&Bs[4*k4+3][tx*4]};
      const float* af = (const float*)av;
      const float* bf = (const float*)bv;
      #pragma unroll
      for (int ks = 0; ks < 4; ks++)
        #pragma unroll
        for (int r = 0; r < 4; r++)
          #pragma unroll
          for (int cc = 0; cc < 4; cc++)
            acc[r][cc] += af[r*4+ks] * bf[ks*4+cc];
    }
    __syncthreads();
  }
  for (int ri = 0; ri < 4; ri++)
    for (int ci = 0; ci < 4; ci++)
      HALL[((size_t)ht*1024 + ne0 + ty*4 + ri)*64 + tx*4 + ci] = acc[ri][ci];
}

// ---------------- K5: qattn gates -> WSRC/WDST ----------------
__global__ void k_qattn(const float* __restrict__ qv, const float* __restrict__ W1,
                        const float* __restrict__ W2, const float* __restrict__ at,
                        float* __restrict__ WSRC, float* __restrict__ WDST){
  int ht = blockIdx.x;    // 12
  int f = threadIdx.x;    // 128
  __shared__ float qv_s[8][512];
  __shared__ float qg1[8][128];
  for (int idx = f; idx < 4096; idx += 128) qv_s[idx >> 9][idx & 511] = qv[idx];
  __syncthreads();
  const float* w1 = W1 + (size_t)ht*512*128;
  const float* w2 = W2 + (size_t)ht*128*128;
  float acc[8] = {};
  for (int k = 0; k < 512; k++){
    float wv = w1[(size_t)k*128 + f];
    #pragma unroll
    for (int n = 0; n < 8; n++) acc[n] += qv_s[n][k] * wv;
  }
  #pragma unroll
  for (int n = 0; n < 8; n++) qg1[n][f] = fmaxf(acc[n], 0.f);
  __syncthreads();
  float acc2[8] = {};
  for (int g = 0; g < 128; g++){
    float wv = w2[(size_t)g*128 + f];
    #pragma unroll
    for (int n = 0; n < 8; n++) acc2[n] += qg1[n][g] * wv;
  }
  float av = at[ht*128 + f];
  #pragma unroll
  for (int n = 0; n < 8; n++){
    float coef = sigm(acc2[n]) * av;
    if (f < 64) WSRC[(ht*8 + n)*64 + f] = coef;
    else        WDST[(ht*8 + n)*64 + f - 64] = coef;
  }
}

// ---------------- K6: src/dst projections ----------------
__global__ void k_srcdst(const float* __restrict__ HALL, const float* __restrict__ WSRC,
                         const float* __restrict__ WDST, float* __restrict__ SRC,
                         float* __restrict__ DST){
  int b = blockIdx.x;     // ht*8+n, 96
  int e = threadIdx.x;    // 128
  __shared__ float w1[64], w2[64];
  if (e < 64) w1[e] = WSRC[b*64 + e]; else w2[e-64] = WDST[b*64 + e - 64];
  __syncthreads();
  int ht = b >> 3, n = b & 7;
  const float* h = HALL + ((size_t)ht*1024 + n*128 + e)*64;
  float s = 0.f, d = 0.f;
  #pragma unroll 8
  for (int f = 0; f < 64; f++){ float hv = h[f]; s += hv*w1[f]; d += hv*w2[f]; }
  SRC[b*128 + e] = s; DST[b*128 + e] = d;
}

// ---------------- K7: typed scores -> softmax -> heads -> entity_state2 ----------------
__global__ void k_attn(const float* __restrict__ HALL, const float* __restrict__ SRC,
                       const float* __restrict__ DST, const float* __restrict__ AM,
                       const int* __restrict__ adj, float* __restrict__ ES2,
                       float* __restrict__ out_ent){
  int b = blockIdx.x;                  // 256 = h(4) x n(8) x chunk(8)
  int h = b >> 6, n = (b >> 3) & 7, chunk = b & 7;
  int i0 = chunk*16;
  int tid = threadIdx.x;               // 128
  __shared__ float dst_l[3][128];
  __shared__ float src_l[3][16];
  __shared__ float hl[128][65];
  __shared__ float coef_l[128];
  __shared__ float redbuf[2];
  for (int idx = tid; idx < 384; idx += 128){
    int t = idx >> 7, j = idx & 127;
    dst_l[t][j] = DST[((h*3 + t)*8 + n)*128 + j];
  }
  if (tid < 48){
    int t = tid >> 4, r = tid & 15;
    src_l[t][r] = SRC[((h*3 + t)*8 + n)*128 + i0 + r];
  }
  for (int idx = tid; idx < 8192; idx += 128){
    int j = idx >> 6, f = idx & 63;
    hl[j][f] = HALL[((size_t)(h*3 + 2)*1024 + n*128 + j)*64 + f] * AM[n*128 + j];
  }
  __syncthreads();
  const int* arow = adj + (size_t)n*128*128;
  for (int r = 0; r < 16; r++){
    int i = i0 + r;
    int a = arow[(size_t)i*128 + tid];
    float s;
    if (a > 0){
      float v = src_l[a-1][r] + dst_l[a-1][tid];
      s = v > 0.f ? v : 0.2f*v;
    } else s = -1e30f;
    float m = s;
    #pragma unroll
    for (int o = 32; o > 0; o >>= 1) m = fmaxf(m, __shfl_xor(m, o, 64));
    int w = tid >> 6;
    if ((tid & 63) == 0) redbuf[w] = m;
    __syncthreads();
    float mx = fmaxf(redbuf[0], redbuf[1]);
    float p = expf(s - mx);
    float ps = p;
    #pragma unroll
    for (int o = 32; o > 0; o >>= 1) ps += __shfl_xor(ps, o, 64);
    __syncthreads();
    if ((tid & 63) == 0) redbuf[w] = ps;
    __syncthreads();
    float denom = redbuf[0] + redbuf[1];
    coef_l[tid] = p / denom;
    __syncthreads();
    if (tid < 64){
      float acc = 0.f;
      for (int j = 0; j < 128; j++) acc += coef_l[j] * hl[j][tid];
      float v = fmaxf(acc, 0.f);
      size_t oidx = ((size_t)n*128 + i)*256 + h*64 + tid;
      ES2[oidx] = v;
      out_ent[oidx] = v;
    }
    __syncthreads();
  }
}

// ---------------- K8: expand entities back to tokens, build LSTM input ----------------
__global__ void k_expand(const float* __restrict__ ES2, const float* __restrict__ emap,
                         const float* __restrict__ doc, float* __restrict__ INP){
  int b = blockIdx.x;       // n*512+l, 4096
  int n = b >> 9, l = b & 511;
  int tid = threadIdx.x;    // 256
  __shared__ float mcol[128];
  if (tid < 128) mcol[tid] = emap[((size_t)n*128 + tid)*512 + l];
  __syncthreads();
  float acc = 0.f;
  const float* e2 = ES2 + (size_t)n*128*256 + tid;
  for (int e = 0; e < 128; e++){
    float m = mcol[e];
    if (m != 0.f) acc += m * e2[(size_t)e*256];   // uniform branch
  }
  float* o = INP + (size_t)b*512;
  o[tid] = acc;
  o[256 + tid] = doc[(size_t)b*256 + tid];
}

// ---------------- K9: input-projection GEMMs (both dirs), bias folded ----------------
__global__ void k_gatein(const float* __restrict__ INP, const float* __restrict__ Wf,
                         const float* __restrict__ Wb, const float* __restrict__ bihf,
                         const float* __restrict__ bhhf, const float* __restrict__ bihb,
                         const float* __restrict__ bhhb, float* __restrict__ GF,
                         float* __restrict__ GB){
  int mt = blockIdx.x, gt = blockIdx.y, dir = blockIdx.z;
  const float* W = dir ? Wb : Wf;
  float* Gout = dir ? GB : GF;
  const float* bi = dir ? bihb : bihf;
  const float* bh = dir ? bhhb : bhhf;
  int tid = threadIdx.x;   // 256
  int ty = tid >> 4, tx = tid & 15;
  __shared__ float As[64][68];
  __shared__ float Bs[64][68];
  int m0 = mt*64, g0 = gt*64;
  float acc[4][4] = {};
  for (int k0 = 0; k0 < 512; k0 += 64){
    for (int idx = tid; idx < 4096; idx += 256){
      int r = idx >> 6, k = idx & 63;
      As[r][k] = INP[(size_t)(m0 + r)*512 + k0 + k];
    }
    for (int idx = tid; idx < 4096; idx += 256){
      int c = idx >> 6, k = idx & 63;
      Bs[k][c] = W[(size_t)(g0 + c)*512 + k0 + k];
    }
    __syncthreads();
    const float4* A0 = (const float4*)&As[ty*4+0][0];
    const float4* A1 = (const float4*)&As[ty*4+1][0];
    const float4* A2 = (const float4*)&As[ty*4+2][0];
    const float4* A3 = (const float4*)&As[ty*4+3][0];
    #pragma unroll
    for (int k4 = 0; k4 < 16; k4++){
      float4 av[4] = {A0[k4], A1[k4], A2[k4], A3[k4]};
      float4 bv[4] = {*(const float4*)&Bs[4*k4+0][tx*4], *(const float4*)&Bs[4*k4+1][tx*4],
                      *(const float4*)&Bs[4*k4+2][tx*4], *(const float4*)&Bs[4*k4+3][tx*4]};
      const float* af = (const float*)av;
      const float* bf = (const float*)bv;
      #pragma unroll
      for (int ks = 0; ks < 4; ks++)
        #pragma unroll
        for (int r = 0; r < 4; r++)
          #pragma unroll
          for (int cc = 0; cc < 4; cc++)
            acc[r][cc] += af[r*4+ks] * bf[ks*4+cc];
    }
    __syncthreads();
  }
  for (int ri = 0; ri < 4; ri++)
    for (int ci = 0; ci < 4; ci++){
      int g = g0 + tx*4 + ci;
      Gout[(size_t)(m0 + ty*4 + ri)*512 + g] = acc[ri][ci] + bi[g] + bh[g];
    }
}

// ---------------- K10: LSTM recurrence ----------------
// 16 blocks (n x dir) x 512 threads. Thread (j = tid>>2, s = tid&3) computes
// ALL 4 gates of hidden unit j over k-slice [32s, 32s+32). Partial sums
// reduced across the 4 slice-lanes with quad_perm DPP (VALU only, no DS).
// All 4 lanes then redundantly compute the elementwise update; lane s==0
// writes h (f16, LDS double-buffer) and the f32 output. One barrier/step.
__global__ __launch_bounds__(512) void k_lstm(const float* __restrict__ GF,
                                              const float* __restrict__ GB,
                                              const float* __restrict__ Whhf,
                                              const float* __restrict__ Whhb,
                                              float* __restrict__ out){
  int b = blockIdx.x;          // 16
  int dir = b >> 3, n = b & 7;
  const float* G = dir ? GB : GF;
  const float* Whh = dir ? Whhb : Whhf;
  int tid = threadIdx.x;       // 512
  int j = tid >> 2;            // unit 0..127
  int s = tid & 3;             // k-slice
  bool wlane = (s == 0);

  // weights: rows q*128+j, cols [32s, 32s+32) -> 4 gates x 16 h2
  h2 wreg[4][16];
  #pragma unroll
  for (int q = 0; q < 4; q++)
    #pragma unroll
    for (int kk = 0; kk < 16; kk++){
      const float* wp = Whh + (size_t)(q*128 + j)*128 + 32*s + 2*kk;
      h2 p; p[0] = (_Float16)wp[0]; p[1] = (_Float16)wp[1];
      wreg[q][kk] = p;
    }

  __shared__ __align__(16) _Float16 h_l[2][128];
  if (tid < 128) h_l[0][tid] = (_Float16)0.f;

  const float* Grow = G + (size_t)n*512*512 + j;
  auto gload = [&](int t, float* gv){
    int tt = dir ? (511 - t) : t;
    const float* p = Grow + (size_t)tt*512;
    gv[0] = p[0]; gv[1] = p[128]; gv[2] = p[256]; gv[3] = p[384];
  };
  float gcur[4], gnxt[4];
  gload(0, gcur); gload(1, gnxt);
  float c = 0.f;
  float* outbase = out + (size_t)n*512*256 + dir*128 + j;
  __syncthreads();

  for (int t = 0; t < 512; t++){
    int rb = t & 1, wb = rb ^ 1;
    float gpre[4] = {0.f, 0.f, 0.f, 0.f};
    if (t + 2 < 512) gload(t + 2, gpre);

    // MV partials: acc[q] = Whh[q*128+j, 32s..32s+32) . h[32s..32s+32)
    const uint4* hb = (const uint4*)(&h_l[rb][0]);
    uint4 hv[4];
    #pragma unroll
    for (int r = 0; r < 4; r++) hv[r] = hb[4*s + r];
    float acc[4];
    #pragma unroll
    for (int q = 0; q < 4; q++){
      float a = 0.f;
      #pragma unroll
      for (int r = 0; r < 4; r++){
        a = fdot2(wreg[q][4*r+0], u2h(hv[r].x), a);
        a = fdot2(wreg[q][4*r+1], u2h(hv[r].y), a);
        a = fdot2(wreg[q][4*r+2], u2h(hv[r].z), a);
        a = fdot2(wreg[q][4*r+3], u2h(hv[r].w), a);
      }
      acc[q] = a;
    }
    // quad reduce across s (xor1, xor2) - VALU DPP, all 4 lanes get full sums
    #pragma unroll
    for (int q = 0; q < 4; q++){
      acc[q] += qperm<0xB1>(acc[q]);
      acc[q] += qperm<0x4E>(acc[q]);
      acc[q] += gcur[q];
    }
    c = fsigm(acc[1]) * c + fsigm(acc[0]) * ftanh(acc[2]);
    float hval = fsigm(acc[3]) * ftanh(c);
    if (wlane){
      h_l[wb][j] = (_Float16)hval;
      int tt = dir ? (511 - t) : t;
      outbase[(size_t)tt * 256] = hval;
    }
    #pragma unroll
    for (int q = 0; q < 4; q++){ gcur[q] = gnxt[q]; gnxt[q] = gpre[q]; }
    __syncthreads();
  }
}

extern "C" void kernel_launch(void* const* d_in, const int* in_sizes, int n_in,
                              void* d_out, int out_size, void* d_ws, size_t ws_size,
                              hipStream_t stream){
  const float* doc   = (const float*)d_in[0];
  const float* qvec  = (const float*)d_in[1];
  const float* emap  = (const float*)d_in[3];
  const float* emask = (const float*)d_in[4];
  const float* qw    = (const float*)d_in[5];
  const float* Wt    = (const float*)d_in[6];
  const float* at    = (const float*)d_in[7];
  const float* qa1   = (const float*)d_in[8];
  const float* qa2   = (const float*)d_in[9];
  const float* Wihf  = (const float*)d_in[10];
  const float* Whhf  = (const float*)d_in[11];
  const float* bihf  = (const float*)d_in[12];
  const float* bhhf  = (const float*)d_in[13];
  const float* Wihb  = (const float*)d_in[14];
  const float* Whhb  = (const float*)d_in[15];
  const float* bihb  = (const float*)d_in[16];
  const float* bhhb  = (const float*)d_in[17];
  const int*   adj   = (const int*)d_in[19];

  float* out = (float*)d_out;
  float* out_doc = out;                         // 8*512*256
  float* out_ent = out + 8*512*256;             // 8*128*256
  float* out_sm  = out_ent + 8*128*256;         // 8*128

  float* w = (float*)d_ws;
  float* ES   = w; w += 8*128*512;
  float* QRY  = w; w += 8*512;
  float* AM   = w; w += 8*128;
  float* HALL = w; w += 12*1024*64;
  float* WSRC = w; w += 12*8*64;
  float* WDST = w; w += 12*8*64;
  float* SRC  = w; w += 12*8*128;
  float* DST  = w; w += 12*8*128;
  float* ES2  = w; w += 8*128*256;
  float* INP  = w; w += 8*512*512;
  float* GF   = w; w += 8*512*512;
  float* GB   = w; w += 8*512*512;

  hipLaunchKernelGGL(k_ent_state, dim3(1024), dim3(256), 0, stream, doc, emap, ES);
  hipLaunchKernelGGL(k_query,     dim3(8),    dim3(512), 0, stream, qvec, qw, QRY);
  hipLaunchKernelGGL(k_qscore,    dim3(8),    dim3(128), 0, stream, ES, QRY, emask, out_sm, AM);
  hipLaunchKernelGGL(k_hall,      dim3(16,12),dim3(256), 0, stream, ES, Wt, HALL);
  hipLaunchKernelGGL(k_qattn,     dim3(12),   dim3(128), 0, stream, qvec, qa1, qa2, at, WSRC, WDST);
  hipLaunchKernelGGL(k_srcdst,    dim3(96),   dim3(128), 0, stream, HALL, WSRC, WDST, SRC, DST);
  hipLaunchKernelGGL(k_attn,      dim3(256),  dim3(128), 0, stream, HALL, SRC, DST, AM, adj, ES2, out_ent);
  hipLaunchKernelGGL(k_expand,    dim3(4096), dim3(256), 0, stream, ES2, emap, doc, INP);
  hipLaunchKernelGGL(k_gatein,    dim3(64,8,2), dim3(256), 0, stream, INP, Wihf, Wihb, bihf, bhhf, bihb, bhhb, GF, GB);
  hipLaunchKernelGGL(k_lstm,      dim3(16),   dim3(512), 0, stream, GF, GB, Whhf, Whhb, out_doc);
}

// Round 4
// 544.492 us; speedup vs baseline: 1.8708x; 1.1055x over previous
//
#include <hip/hip_runtime.h>
#include <math.h>

typedef _Float16 h2 __attribute__((ext_vector_type(2)));
typedef __attribute__((ext_vector_type(8))) short bf16x8;
typedef __attribute__((ext_vector_type(4))) float f32x4;

__device__ __forceinline__ float sigm(float x){ return 1.f/(1.f+expf(-x)); }

__device__ __forceinline__ float fsigm(float x){
  float e = __expf(-x);
  return __builtin_amdgcn_rcpf(1.f + e);
}
__device__ __forceinline__ float ftanh(float x){
  float xx = fminf(fmaxf(x, -15.f), 15.f);
  float e = __expf(2.f * xx);
  return 1.f - 2.f * __builtin_amdgcn_rcpf(e + 1.f);
}
__device__ __forceinline__ h2 u2h(unsigned u){
  union { unsigned u; h2 h; } x; x.u = u; return x.h;
}
// quad_perm DPP helper (VALU cross-lane, no DS pipe)
template<int CTRL>
__device__ __forceinline__ float qperm(float v){
  return __int_as_float(__builtin_amdgcn_mov_dpp(__float_as_int(v), CTRL, 0xf, 0xf, true));
}
__device__ __forceinline__ unsigned short f2bf(float f){
  union{float f; unsigned u;} x; x.f = f;
  unsigned r = x.u + 0x7FFF + ((x.u >> 16) & 1);
  return (unsigned short)(r >> 16);
}

// ---------------- K1: entity max/mean pooling ----------------
__global__ void k_ent_state(const float* __restrict__ doc, const float* __restrict__ emap,
                            float* __restrict__ ES){
  int ne = blockIdx.x;            // n*128+e
  int n = ne >> 7;
  int tid = threadIdx.x;          // 256 threads = d
  __shared__ float mrow_s[512];
  for (int l = tid; l < 512; l += 256) mrow_s[l] = emap[(size_t)ne*512 + l];
  __syncthreads();
  const float* dbase = doc + (size_t)n*512*256 + tid;
  float sum = 0.f, mx = -3.402823e38f, msum = 0.f;
  int cnt = 0;
  for (int l = 0; l < 512; l++){
    float m = mrow_s[l];
    if (m != 0.f){                // uniform branch across block
      float v = m * dbase[(size_t)l*256];
      sum += v; mx = fmaxf(mx, v); msum += m; cnt++;
    }
  }
  if (cnt < 512) mx = fmaxf(mx, 0.f);
  float elen = (msum == 0.f) ? 1.f : msum;
  float* o = ES + (size_t)ne*512;
  o[tid] = mx;
  o[256 + tid] = sum / elen;
}

// ---------------- K2: query = query_vec @ query_weight ----------------
__global__ void k_query(const float* __restrict__ qv, const float* __restrict__ qw,
                        float* __restrict__ Q){
  int n = blockIdx.x; int tid = threadIdx.x;    // 512
  __shared__ float q[512];
  q[tid] = qv[n*512 + tid];
  __syncthreads();
  float acc = 0.f;
  for (int k = 0; k < 512; k++) acc += q[k] * qw[(size_t)k*512 + tid];
  Q[n*512 + tid] = acc;
}

// ---------------- K3: query scores, softmask, adj_mask ----------------
__global__ void k_qscore(const float* __restrict__ ES, const float* __restrict__ Q,
                         const float* __restrict__ emask, float* __restrict__ sm_out,
                         float* __restrict__ AM){
  int n = blockIdx.x; int e = threadIdx.x;      // 128
  __shared__ float q[512];
  for (int k = e; k < 512; k += 128) q[k] = Q[n*512 + k];
  __syncthreads();
  const float* es = ES + ((size_t)(n*128 + e))*512;
  float acc = 0.f;
  for (int k = 0; k < 512; k++) acc += es[k] * q[k];
  float s = (acc * (1.f/512.f)) * emask[n*128 + e];
  sm_out[n*128 + e] = s;
  AM[n*128 + e] = sigm(s);
}

// ---------------- K4: h_all = ES @ W_type  (12 x [1024x512x64]) ----------------
__global__ void k_hall(const float* __restrict__ ES, const float* __restrict__ Wt,
                       float* __restrict__ HALL){
  int net = blockIdx.x;   // 16 tiles of 64 ne-rows
  int ht  = blockIdx.y;   // 12
  int tid = threadIdx.x;  // 256
  int ty = tid >> 4, tx = tid & 15;
  __shared__ float As[64][68];
  __shared__ float Bs[64][68];
  int ne0 = net*64;
  float acc[4][4] = {};
  for (int k0 = 0; k0 < 512; k0 += 64){
    for (int idx = tid; idx < 4096; idx += 256){
      int r = idx >> 6, k = idx & 63;
      As[r][k] = ES[(size_t)(ne0 + r)*512 + k0 + k];
    }
    for (int idx = tid; idx < 4096; idx += 256){
      int k = idx >> 6, f = idx & 63;
      Bs[k][f] = Wt[((size_t)ht*512 + k0 + k)*64 + f];
    }
    __syncthreads();
    const float4* A0 = (const float4*)&As[ty*4+0][0];
    const float4* A1 = (const float4*)&As[ty*4+1][0];
    const float4* A2 = (const float4*)&As[ty*4+2][0];
    const float4* A3 = (const float4*)&As[ty*4+3][0];
    #pragma unroll
    for (int k4 = 0; k4 < 16; k4++){
      float4 av[4] = {A0[k4], A1[k4], A2[k4], A3[k4]};
      float4 bv[4] = {*(const float4*)&Bs[4*k4+0][tx*4], *(const float4*)&Bs[4*k4+1][tx*4],
                      *(const float4*)&Bs[4*k4+2][tx*4], *(const float4*)&Bs[4*k4+3][tx*4]};
      const float* af = (const float*)av;
      const float* bf = (const float*)bv;
      #pragma unroll
      for (int ks = 0; ks < 4; ks++)
        #pragma unroll
        for (int r = 0; r < 4; r++)
          #pragma unroll
          for (int cc = 0; cc < 4; cc++)
            acc[r][cc] += af[r*4+ks] * bf[ks*4+cc];
    }
    __syncthreads();
  }
  for (int ri = 0; ri < 4; ri++)
    for (int ci = 0; ci < 4; ci++)
      HALL[((size_t)ht*1024 + ne0 + ty*4 + ri)*64 + tx*4 + ci] = acc[ri][ci];
}

// ---------------- K5: qattn gates -> WSRC/WDST ----------------
__global__ void k_qattn(const float* __restrict__ qv, const float* __restrict__ W1,
                        const float* __restrict__ W2, const float* __restrict__ at,
                        float* __restrict__ WSRC, float* __restrict__ WDST){
  int ht = blockIdx.x;    // 12
  int f = threadIdx.x;    // 128
  __shared__ float qv_s[8][512];
  __shared__ float qg1[8][128];
  for (int idx = f; idx < 4096; idx += 128) qv_s[idx >> 9][idx & 511] = qv[idx];
  __syncthreads();
  const float* w1 = W1 + (size_t)ht*512*128;
  const float* w2 = W2 + (size_t)ht*128*128;
  float acc[8] = {};
  for (int k = 0; k < 512; k++){
    float wv = w1[(size_t)k*128 + f];
    #pragma unroll
    for (int n = 0; n < 8; n++) acc[n] += qv_s[n][k] * wv;
  }
  #pragma unroll
  for (int n = 0; n < 8; n++) qg1[n][f] = fmaxf(acc[n], 0.f);
  __syncthreads();
  float acc2[8] = {};
  for (int g = 0; g < 128; g++){
    float wv = w2[(size_t)g*128 + f];
    #pragma unroll
    for (int n = 0; n < 8; n++) acc2[n] += qg1[n][g] * wv;
  }
  float av = at[ht*128 + f];
  #pragma unroll
  for (int n = 0; n < 8; n++){
    float coef = sigm(acc2[n]) * av;
    if (f < 64) WSRC[(ht*8 + n)*64 + f] = coef;
    else        WDST[(ht*8 + n)*64 + f - 64] = coef;
  }
}

// ---------------- K6: src/dst projections ----------------
__global__ void k_srcdst(const float* __restrict__ HALL, const float* __restrict__ WSRC,
                         const float* __restrict__ WDST, float* __restrict__ SRC,
                         float* __restrict__ DST){
  int b = blockIdx.x;     // ht*8+n, 96
  int e = threadIdx.x;    // 128
  __shared__ float w1[64], w2[64];
  if (e < 64) w1[e] = WSRC[b*64 + e]; else w2[e-64] = WDST[b*64 + e - 64];
  __syncthreads();
  int ht = b >> 3, n = b & 7;
  const float* h = HALL + ((size_t)ht*1024 + n*128 + e)*64;
  float s = 0.f, d = 0.f;
  #pragma unroll 8
  for (int f = 0; f < 64; f++){ float hv = h[f]; s += hv*w1[f]; d += hv*w2[f]; }
  SRC[b*128 + e] = s; DST[b*128 + e] = d;
}

// ---------------- K7: typed scores -> softmax -> heads -> entity_state2 ----------------
__global__ void k_attn(const float* __restrict__ HALL, const float* __restrict__ SRC,
                       const float* __restrict__ DST, const float* __restrict__ AM,
                       const int* __restrict__ adj, float* __restrict__ ES2,
                       float* __restrict__ out_ent){
  int b = blockIdx.x;                  // 256 = h(4) x n(8) x chunk(8)
  int h = b >> 6, n = (b >> 3) & 7, chunk = b & 7;
  int i0 = chunk*16;
  int tid = threadIdx.x;               // 128
  __shared__ float dst_l[3][128];
  __shared__ float src_l[3][16];
  __shared__ float hl[128][65];
  __shared__ float coef_l[128];
  __shared__ float redbuf[2];
  for (int idx = tid; idx < 384; idx += 128){
    int t = idx >> 7, j = idx & 127;
    dst_l[t][j] = DST[((h*3 + t)*8 + n)*128 + j];
  }
  if (tid < 48){
    int t = tid >> 4, r = tid & 15;
    src_l[t][r] = SRC[((h*3 + t)*8 + n)*128 + i0 + r];
  }
  for (int idx = tid; idx < 8192; idx += 128){
    int j = idx >> 6, f = idx & 63;
    hl[j][f] = HALL[((size_t)(h*3 + 2)*1024 + n*128 + j)*64 + f] * AM[n*128 + j];
  }
  __syncthreads();
  const int* arow = adj + (size_t)n*128*128;
  for (int r = 0; r < 16; r++){
    int i = i0 + r;
    int a = arow[(size_t)i*128 + tid];
    float s;
    if (a > 0){
      float v = src_l[a-1][r] + dst_l[a-1][tid];
      s = v > 0.f ? v : 0.2f*v;
    } else s = -1e30f;
    float m = s;
    #pragma unroll
    for (int o = 32; o > 0; o >>= 1) m = fmaxf(m, __shfl_xor(m, o, 64));
    int w = tid >> 6;
    if ((tid & 63) == 0) redbuf[w] = m;
    __syncthreads();
    float mx = fmaxf(redbuf[0], redbuf[1]);
    float p = expf(s - mx);
    float ps = p;
    #pragma unroll
    for (int o = 32; o > 0; o >>= 1) ps += __shfl_xor(ps, o, 64);
    __syncthreads();
    if ((tid & 63) == 0) redbuf[w] = ps;
    __syncthreads();
    float denom = redbuf[0] + redbuf[1];
    coef_l[tid] = p / denom;
    __syncthreads();
    if (tid < 64){
      float acc = 0.f;
      for (int j = 0; j < 128; j++) acc += coef_l[j] * hl[j][tid];
      float v = fmaxf(acc, 0.f);
      size_t oidx = ((size_t)n*128 + i)*256 + h*64 + tid;
      ES2[oidx] = v;
      out_ent[oidx] = v;
    }
    __syncthreads();
  }
}

// ---------------- K8: expand entities back to tokens, build LSTM input ----------------
__global__ void k_expand(const float* __restrict__ ES2, const float* __restrict__ emap,
                         const float* __restrict__ doc, float* __restrict__ INP){
  int b = blockIdx.x;       // n*512+l, 4096
  int n = b >> 9, l = b & 511;
  int tid = threadIdx.x;    // 256
  __shared__ float mcol[128];
  if (tid < 128) mcol[tid] = emap[((size_t)n*128 + tid)*512 + l];
  __syncthreads();
  float acc = 0.f;
  const float* e2 = ES2 + (size_t)n*128*256 + tid;
  for (int e = 0; e < 128; e++){
    float m = mcol[e];
    if (m != 0.f) acc += m * e2[(size_t)e*256];   // uniform branch
  }
  float* o = INP + (size_t)b*512;
  o[tid] = acc;
  o[256 + tid] = doc[(size_t)b*256 + tid];
}

// ---------------- K9: input-projection GEMMs via bf16 MFMA ----------------
// C[m][g] = sum_k INP[m][k] * W[g][k] + bi[g] + bh[g]
// block 256 = 4 waves in 2x2 arrangement; wave computes 32x32 via 2x2 MFMA
// 16x16x32 tiles over K=512. Fragments loaded directly from global (8
// contiguous f32 per lane), converted to bf16 in-register. No LDS.
__global__ __launch_bounds__(256) void k_gatein(const float* __restrict__ INP,
                         const float* __restrict__ Wf, const float* __restrict__ Wb,
                         const float* __restrict__ bihf, const float* __restrict__ bhhf,
                         const float* __restrict__ bihb, const float* __restrict__ bhhb,
                         float* __restrict__ GF, float* __restrict__ GB){
  int mt = blockIdx.x, gt = blockIdx.y, dir = blockIdx.z;
  const float* W = dir ? Wb : Wf;
  float* Gout = dir ? GB : GF;
  const float* bi = dir ? bihb : bihf;
  const float* bh = dir ? bhhb : bhhf;
  int tid = threadIdx.x;
  int lane = tid & 63, w = tid >> 6;
  int wm = w >> 1, wg = w & 1;
  int m0 = mt*64 + wm*32;
  int g0 = gt*64 + wg*32;
  int lr = lane & 15, lk8 = (lane >> 4) * 8;

  const float* a0p = INP + (size_t)(m0 + lr)*512 + lk8;
  const float* a1p = a0p + (size_t)16*512;
  const float* b0p = W   + (size_t)(g0 + lr)*512 + lk8;
  const float* b1p = b0p + (size_t)16*512;

  f32x4 acc[2][2] = {};
  for (int k0 = 0; k0 < 512; k0 += 32){
    bf16x8 af[2], bfr[2];
    {
      float4 u = *(const float4*)a0p, v = *(const float4*)(a0p + 4);
      bf16x8 r; r[0]=(short)f2bf(u.x); r[1]=(short)f2bf(u.y); r[2]=(short)f2bf(u.z); r[3]=(short)f2bf(u.w);
      r[4]=(short)f2bf(v.x); r[5]=(short)f2bf(v.y); r[6]=(short)f2bf(v.z); r[7]=(short)f2bf(v.w);
      af[0]=r;
    }
    {
      float4 u = *(const float4*)a1p, v = *(const float4*)(a1p + 4);
      bf16x8 r; r[0]=(short)f2bf(u.x); r[1]=(short)f2bf(u.y); r[2]=(short)f2bf(u.z); r[3]=(short)f2bf(u.w);
      r[4]=(short)f2bf(v.x); r[5]=(short)f2bf(v.y); r[6]=(short)f2bf(v.z); r[7]=(short)f2bf(v.w);
      af[1]=r;
    }
    {
      float4 u = *(const float4*)b0p, v = *(const float4*)(b0p + 4);
      bf16x8 r; r[0]=(short)f2bf(u.x); r[1]=(short)f2bf(u.y); r[2]=(short)f2bf(u.z); r[3]=(short)f2bf(u.w);
      r[4]=(short)f2bf(v.x); r[5]=(short)f2bf(v.y); r[6]=(short)f2bf(v.z); r[7]=(short)f2bf(v.w);
      bfr[0]=r;
    }
    {
      float4 u = *(const float4*)b1p, v = *(const float4*)(b1p + 4);
      bf16x8 r; r[0]=(short)f2bf(u.x); r[1]=(short)f2bf(u.y); r[2]=(short)f2bf(u.z); r[3]=(short)f2bf(u.w);
      r[4]=(short)f2bf(v.x); r[5]=(short)f2bf(v.y); r[6]=(short)f2bf(v.z); r[7]=(short)f2bf(v.w);
      bfr[1]=r;
    }
    a0p += 32; a1p += 32; b0p += 32; b1p += 32;
    #pragma unroll
    for (int im = 0; im < 2; im++)
      #pragma unroll
      for (int ig = 0; ig < 2; ig++)
        acc[im][ig] = __builtin_amdgcn_mfma_f32_16x16x32_bf16(af[im], bfr[ig], acc[im][ig], 0, 0, 0);
  }
  // C/D layout: col = lane&15, row = (lane>>4)*4 + reg   [m89 verified]
  int crow = (lane >> 4) * 4;
  int ccol = lane & 15;
  #pragma unroll
  for (int im = 0; im < 2; im++)
    #pragma unroll
    for (int ig = 0; ig < 2; ig++){
      int g = g0 + ig*16 + ccol;
      float bias = bi[g] + bh[g];
      #pragma unroll
      for (int r = 0; r < 4; r++){
        int m = m0 + im*16 + crow + r;
        Gout[(size_t)m*512 + g] = acc[im][ig][r] + bias;
      }
    }
}

// ---------------- K10: LSTM recurrence ----------------
// 16 blocks (n x dir) x 256 threads (4 waves). Thread (j = tid>>1, s = tid&1)
// computes all 4 gates of unit j over k-slice [64s, 64s+64) with v_pk_fma_f16
// (native _Float16x2 math). Reduce across the 2 slice-lanes with one
// quad_perm DPP. h double-buffered in LDS f16; G pointer-marched with
// immediate offsets, prefetch depth 2; step body unrolled 2x so buffer
// indices and prefetch registers are static. One barrier per step.
__global__ __launch_bounds__(256) void k_lstm(const float* __restrict__ GF,
                                              const float* __restrict__ GB,
                                              const float* __restrict__ Whhf,
                                              const float* __restrict__ Whhb,
                                              float* __restrict__ out){
  int b = blockIdx.x;          // 16
  int dir = b >> 3, n = b & 7;
  const float* G = dir ? GB : GF;
  const float* Whh = dir ? Whhb : Whhf;
  int tid = threadIdx.x;       // 256
  int j = tid >> 1;            // unit 0..127
  int s = tid & 1;             // k-slice half

  // weights: rows q*128+j, cols [64s, 64s+64) -> 4 gates x 32 h2
  h2 wreg[4][32];
  #pragma unroll
  for (int q = 0; q < 4; q++){
    const float* wp = Whh + (size_t)(q*128 + j)*128 + 64*s;
    #pragma unroll
    for (int kk = 0; kk < 32; kk++){
      h2 p; p[0] = (_Float16)wp[2*kk]; p[1] = (_Float16)wp[2*kk+1];
      wreg[q][kk] = p;
    }
  }

  __shared__ __align__(16) _Float16 h_l[2][128];
  if (tid < 128) h_l[0][tid] = (_Float16)0.f;

  const float* Gp = G + (size_t)n*512*512 + (dir ? (size_t)511*512 : 0) + j;
  const int gstep = dir ? -512 : 512;
  float* outp = out + (size_t)n*512*256 + (dir ? (size_t)511*256 : 0) + dir*128 + j;
  const int ostep = dir ? -256 : 256;

  float g0[4], g1[4];
  g0[0]=Gp[0]; g0[1]=Gp[128]; g0[2]=Gp[256]; g0[3]=Gp[384]; Gp += gstep;
  g1[0]=Gp[0]; g1[1]=Gp[128]; g1[2]=Gp[256]; g1[3]=Gp[384]; Gp += gstep;
  float c = 0.f;
  __syncthreads();

#define LSTM_STEP(RB, GREG)                                                    \
  {                                                                            \
    const uint4* hb = (const uint4*)(&h_l[RB][64*s]);                          \
    uint4 hv[8];                                                               \
    _Pragma("unroll")                                                          \
    for (int r = 0; r < 8; r++) hv[r] = hb[r];                                 \
    float gc0 = GREG[0], gc1 = GREG[1], gc2 = GREG[2], gc3 = GREG[3];          \
    GREG[0]=Gp[0]; GREG[1]=Gp[128]; GREG[2]=Gp[256]; GREG[3]=Gp[384];          \
    Gp += gstep;                                                               \
    float accf[4];                                                             \
    _Pragma("unroll")                                                          \
    for (int q = 0; q < 4; q++){                                               \
      h2 a0; a0[0]=(_Float16)0.f; a0[1]=(_Float16)0.f; h2 a1 = a0;             \
      _Pragma("unroll")                                                        \
      for (int r = 0; r < 8; r++){                                             \
        a0 += wreg[q][4*r+0] * u2h(hv[r].x);                                   \
        a1 += wreg[q][4*r+1] * u2h(hv[r].y);                                   \
        a0 += wreg[q][4*r+2] * u2h(hv[r].z);                                   \
        a1 += wreg[q][4*r+3] * u2h(hv[r].w);                                   \
      }                                                                        \
      h2 hs = a0 + a1;                                                         \
      accf[q] = (float)hs[0] + (float)hs[1];                                   \
    }                                                                          \
    _Pragma("unroll")                                                          \
    for (int q = 0; q < 4; q++){                                               \
      accf[q] += qperm<0xB1>(accf[q]);                                         \
    }                                                                          \
    float vi = accf[0] + gc0, vf = accf[1] + gc1;                              \
    float vg = accf[2] + gc2, vo = accf[3] + gc3;                              \
    c = fsigm(vf) * c + fsigm(vi) * ftanh(vg);                                 \
    float hval = fsigm(vo) * ftanh(c);                                         \
    if (s == 0) h_l[RB^1][j] = (_Float16)hval;                                 \
    else        *outp = hval;                                                  \
    outp += ostep;                                                             \
    __syncthreads();                                                           \
  }

  for (int t = 0; t < 512; t += 2){
    LSTM_STEP(0, g0)
    LSTM_STEP(1, g1)
  }
#undef LSTM_STEP
}

extern "C" void kernel_launch(void* const* d_in, const int* in_sizes, int n_in,
                              void* d_out, int out_size, void* d_ws, size_t ws_size,
                              hipStream_t stream){
  const float* doc   = (const float*)d_in[0];
  const float* qvec  = (const float*)d_in[1];
  const float* emap  = (const float*)d_in[3];
  const float* emask = (const float*)d_in[4];
  const float* qw    = (const float*)d_in[5];
  const float* Wt    = (const float*)d_in[6];
  const float* at    = (const float*)d_in[7];
  const float* qa1   = (const float*)d_in[8];
  const float* qa2   = (const float*)d_in[9];
  const float* Wihf  = (const float*)d_in[10];
  const float* Whhf  = (const float*)d_in[11];
  const float* bihf  = (const float*)d_in[12];
  const float* bhhf  = (const float*)d_in[13];
  const float* Wihb  = (const float*)d_in[14];
  const float* Whhb  = (const float*)d_in[15];
  const float* bihb  = (const float*)d_in[16];
  const float* bhhb  = (const float*)d_in[17];
  const int*   adj   = (const int*)d_in[19];

  float* out = (float*)d_out;
  float* out_doc = out;                         // 8*512*256
  float* out_ent = out + 8*512*256;             // 8*128*256
  float* out_sm  = out_ent + 8*128*256;         // 8*128

  float* w = (float*)d_ws;
  float* ES   = w; w += 8*128*512;
  float* QRY  = w; w += 8*512;
  float* AM   = w; w += 8*128;
  float* HALL = w; w += 12*1024*64;
  float* WSRC = w; w += 12*8*64;
  float* WDST = w; w += 12*8*64;
  float* SRC  = w; w += 12*8*128;
  float* DST  = w; w += 12*8*128;
  float* ES2  = w; w += 8*128*256;
  float* INP  = w; w += 8*512*512;
  float* GF   = w; w += 8*512*512;
  float* GB   = w; w += 8*512*512;

  hipLaunchKernelGGL(k_ent_state, dim3(1024), dim3(256), 0, stream, doc, emap, ES);
  hipLaunchKernelGGL(k_query,     dim3(8),    dim3(512), 0, stream, qvec, qw, QRY);
  hipLaunchKernelGGL(k_qscore,    dim3(8),    dim3(128), 0, stream, ES, QRY, emask, out_sm, AM);
  hipLaunchKernelGGL(k_hall,      dim3(16,12),dim3(256), 0, stream, ES, Wt, HALL);
  hipLaunchKernelGGL(k_qattn,     dim3(12),   dim3(128), 0, stream, qvec, qa1, qa2, at, WSRC, WDST);
  hipLaunchKernelGGL(k_srcdst,    dim3(96),   dim3(128), 0, stream, HALL, WSRC, WDST, SRC, DST);
  hipLaunchKernelGGL(k_attn,      dim3(256),  dim3(128), 0, stream, HALL, SRC, DST, AM, adj, ES2, out_ent);
  hipLaunchKernelGGL(k_expand,    dim3(4096), dim3(256), 0, stream, ES2, emap, doc, INP);
  hipLaunchKernelGGL(k_gatein,    dim3(64,8,2), dim3(256), 0, stream, INP, Wihf, Wihb, bihf, bhhf, bihb, bhhb, GF, GB);
  hipLaunchKernelGGL(k_lstm,      dim3(16),   dim3(256), 0, stream, GF, GB, Whhf, Whhb, out_doc);
}

// Round 5
// 540.687 us; speedup vs baseline: 1.8840x; 1.0070x over previous
//
#include <hip/hip_runtime.h>
#include <math.h>

typedef _Float16 h2 __attribute__((ext_vector_type(2)));
typedef __attribute__((ext_vector_type(8))) short bf16x8;
typedef __attribute__((ext_vector_type(4))) float f32x4;

__device__ __forceinline__ float sigm(float x){ return 1.f/(1.f+expf(-x)); }

__device__ __forceinline__ float fsigm(float x){
  float e = __expf(-x);
  return __builtin_amdgcn_rcpf(1.f + e);
}
__device__ __forceinline__ float ftanh(float x){
  float xx = fminf(fmaxf(x, -15.f), 15.f);
  float e = __expf(2.f * xx);
  return 1.f - 2.f * __builtin_amdgcn_rcpf(e + 1.f);
}
__device__ __forceinline__ h2 u2h(unsigned u){
  union { unsigned u; h2 h; } x; x.u = u; return x.h;
}
// quad_perm DPP helper (VALU cross-lane, no DS pipe)
template<int CTRL>
__device__ __forceinline__ float qperm(float v){
  return __int_as_float(__builtin_amdgcn_mov_dpp(__float_as_int(v), CTRL, 0xf, 0xf, true));
}
__device__ __forceinline__ unsigned short f2bf(float f){
  union{float f; unsigned u;} x; x.f = f;
  unsigned r = x.u + 0x7FFF + ((x.u >> 16) & 1);
  return (unsigned short)(r >> 16);
}

// ---------------- K1: entity max/mean pooling ----------------
__global__ void k_ent_state(const float* __restrict__ doc, const float* __restrict__ emap,
                            float* __restrict__ ES){
  int ne = blockIdx.x;            // n*128+e
  int n = ne >> 7;
  int tid = threadIdx.x;          // 256 threads = d
  __shared__ float mrow_s[512];
  for (int l = tid; l < 512; l += 256) mrow_s[l] = emap[(size_t)ne*512 + l];
  __syncthreads();
  const float* dbase = doc + (size_t)n*512*256 + tid;
  float sum = 0.f, mx = -3.402823e38f, msum = 0.f;
  int cnt = 0;
  for (int l = 0; l < 512; l++){
    float m = mrow_s[l];
    if (m != 0.f){                // uniform branch across block
      float v = m * dbase[(size_t)l*256];
      sum += v; mx = fmaxf(mx, v); msum += m; cnt++;
    }
  }
  if (cnt < 512) mx = fmaxf(mx, 0.f);
  float elen = (msum == 0.f) ? 1.f : msum;
  float* o = ES + (size_t)ne*512;
  o[tid] = mx;
  o[256 + tid] = sum / elen;
}

// ---------------- K2+K3 merged: query proj + scores + softmask + adj_mask ----------------
__global__ void k_qscore(const float* __restrict__ qv, const float* __restrict__ qw,
                         const float* __restrict__ ES, const float* __restrict__ emask,
                         float* __restrict__ sm_out, float* __restrict__ AM){
  int n = blockIdx.x; int tid = threadIdx.x;    // 512
  __shared__ float qvl[512];
  __shared__ float q[512];
  qvl[tid] = qv[n*512 + tid];
  __syncthreads();
  float acc = 0.f;
  for (int k = 0; k < 512; k++) acc += qvl[k] * qw[(size_t)k*512 + tid];
  q[tid] = acc;
  __syncthreads();
  if (tid < 128){
    int e = tid;
    const float* es = ES + ((size_t)(n*128 + e))*512;
    float a = 0.f;
    for (int k = 0; k < 512; k++) a += es[k] * q[k];
    float s = (a * (1.f/512.f)) * emask[n*128 + e];
    sm_out[n*128 + e] = s;
    AM[n*128 + e] = sigm(s);
  }
}

// ---------------- K4: h_all = ES @ W_type  (12 x [1024x512x64]) ----------------
__global__ void k_hall(const float* __restrict__ ES, const float* __restrict__ Wt,
                       float* __restrict__ HALL){
  int net = blockIdx.x;   // 16 tiles of 64 ne-rows
  int ht  = blockIdx.y;   // 12
  int tid = threadIdx.x;  // 256
  int ty = tid >> 4, tx = tid & 15;
  __shared__ float As[64][68];
  __shared__ float Bs[64][68];
  int ne0 = net*64;
  float acc[4][4] = {};
  for (int k0 = 0; k0 < 512; k0 += 64){
    for (int idx = tid; idx < 4096; idx += 256){
      int r = idx >> 6, k = idx & 63;
      As[r][k] = ES[(size_t)(ne0 + r)*512 + k0 + k];
    }
    for (int idx = tid; idx < 4096; idx += 256){
      int k = idx >> 6, f = idx & 63;
      Bs[k][f] = Wt[((size_t)ht*512 + k0 + k)*64 + f];
    }
    __syncthreads();
    const float4* A0 = (const float4*)&As[ty*4+0][0];
    const float4* A1 = (const float4*)&As[ty*4+1][0];
    const float4* A2 = (const float4*)&As[ty*4+2][0];
    const float4* A3 = (const float4*)&As[ty*4+3][0];
    #pragma unroll
    for (int k4 = 0; k4 < 16; k4++){
      float4 av[4] = {A0[k4], A1[k4], A2[k4], A3[k4]};
      float4 bv[4] = {*(const float4*)&Bs[4*k4+0][tx*4], *(const float4*)&Bs[4*k4+1][tx*4],
                      *(const float4*)&Bs[4*k4+2][tx*4], *(const float4*)&Bs[4*k4+3][tx*4]};
      const float* af = (const float*)av;
      const float* bf = (const float*)bv;
      #pragma unroll
      for (int ks = 0; ks < 4; ks++)
        #pragma unroll
        for (int r = 0; r < 4; r++)
          #pragma unroll
          for (int cc = 0; cc < 4; cc++)
            acc[r][cc] += af[r*4+ks] * bf[ks*4+cc];
    }
    __syncthreads();
  }
  for (int ri = 0; ri < 4; ri++)
    for (int ci = 0; ci < 4; ci++)
      HALL[((size_t)ht*1024 + ne0 + ty*4 + ri)*64 + tx*4 + ci] = acc[ri][ci];
}

// ---------------- K5: qattn gates -> WSRC/WDST ----------------
__global__ void k_qattn(const float* __restrict__ qv, const float* __restrict__ W1,
                        const float* __restrict__ W2, const float* __restrict__ at,
                        float* __restrict__ WSRC, float* __restrict__ WDST){
  int ht = blockIdx.x;    // 12
  int f = threadIdx.x;    // 128
  __shared__ float qv_s[8][512];
  __shared__ float qg1[8][128];
  for (int idx = f; idx < 4096; idx += 128) qv_s[idx >> 9][idx & 511] = qv[idx];
  __syncthreads();
  const float* w1 = W1 + (size_t)ht*512*128;
  const float* w2 = W2 + (size_t)ht*128*128;
  float acc[8] = {};
  for (int k = 0; k < 512; k++){
    float wv = w1[(size_t)k*128 + f];
    #pragma unroll
    for (int n = 0; n < 8; n++) acc[n] += qv_s[n][k] * wv;
  }
  #pragma unroll
  for (int n = 0; n < 8; n++) qg1[n][f] = fmaxf(acc[n], 0.f);
  __syncthreads();
  float acc2[8] = {};
  for (int g = 0; g < 128; g++){
    float wv = w2[(size_t)g*128 + f];
    #pragma unroll
    for (int n = 0; n < 8; n++) acc2[n] += qg1[n][g] * wv;
  }
  float av = at[ht*128 + f];
  #pragma unroll
  for (int n = 0; n < 8; n++){
    float coef = sigm(acc2[n]) * av;
    if (f < 64) WSRC[(ht*8 + n)*64 + f] = coef;
    else        WDST[(ht*8 + n)*64 + f - 64] = coef;
  }
}

// ---------------- K6: src/dst projections ----------------
__global__ void k_srcdst(const float* __restrict__ HALL, const float* __restrict__ WSRC,
                         const float* __restrict__ WDST, float* __restrict__ SRC,
                         float* __restrict__ DST){
  int b = blockIdx.x;     // ht*8+n, 96
  int e = threadIdx.x;    // 128
  __shared__ float w1[64], w2[64];
  if (e < 64) w1[e] = WSRC[b*64 + e]; else w2[e-64] = WDST[b*64 + e - 64];
  __syncthreads();
  int ht = b >> 3, n = b & 7;
  const float* h = HALL + ((size_t)ht*1024 + n*128 + e)*64;
  float s = 0.f, d = 0.f;
  #pragma unroll 8
  for (int f = 0; f < 64; f++){ float hv = h[f]; s += hv*w1[f]; d += hv*w2[f]; }
  SRC[b*128 + e] = s; DST[b*128 + e] = d;
}

// ---------------- K7: typed scores -> softmax -> heads -> entity_state2 ----------------
__global__ void k_attn(const float* __restrict__ HALL, const float* __restrict__ SRC,
                       const float* __restrict__ DST, const float* __restrict__ AM,
                       const int* __restrict__ adj, float* __restrict__ ES2,
                       float* __restrict__ out_ent){
  int b = blockIdx.x;                  // 256 = h(4) x n(8) x chunk(8)
  int h = b >> 6, n = (b >> 3) & 7, chunk = b & 7;
  int i0 = chunk*16;
  int tid = threadIdx.x;               // 128
  __shared__ float dst_l[3][128];
  __shared__ float src_l[3][16];
  __shared__ float hl[128][65];
  __shared__ float coef_l[128];
  __shared__ float redbuf[2];
  for (int idx = tid; idx < 384; idx += 128){
    int t = idx >> 7, j = idx & 127;
    dst_l[t][j] = DST[((h*3 + t)*8 + n)*128 + j];
  }
  if (tid < 48){
    int t = tid >> 4, r = tid & 15;
    src_l[t][r] = SRC[((h*3 + t)*8 + n)*128 + i0 + r];
  }
  for (int idx = tid; idx < 8192; idx += 128){
    int j = idx >> 6, f = idx & 63;
    hl[j][f] = HALL[((size_t)(h*3 + 2)*1024 + n*128 + j)*64 + f] * AM[n*128 + j];
  }
  __syncthreads();
  const int* arow = adj + (size_t)n*128*128;
  for (int r = 0; r < 16; r++){
    int i = i0 + r;
    int a = arow[(size_t)i*128 + tid];
    float s;
    if (a > 0){
      float v = src_l[a-1][r] + dst_l[a-1][tid];
      s = v > 0.f ? v : 0.2f*v;
    } else s = -1e30f;
    float m = s;
    #pragma unroll
    for (int o = 32; o > 0; o >>= 1) m = fmaxf(m, __shfl_xor(m, o, 64));
    int w = tid >> 6;
    if ((tid & 63) == 0) redbuf[w] = m;
    __syncthreads();
    float mx = fmaxf(redbuf[0], redbuf[1]);
    float p = expf(s - mx);
    float ps = p;
    #pragma unroll
    for (int o = 32; o > 0; o >>= 1) ps += __shfl_xor(ps, o, 64);
    __syncthreads();
    if ((tid & 63) == 0) redbuf[w] = ps;
    __syncthreads();
    float denom = redbuf[0] + redbuf[1];
    coef_l[tid] = p / denom;
    __syncthreads();
    if (tid < 64){
      float acc = 0.f;
      for (int j = 0; j < 128; j++) acc += coef_l[j] * hl[j][tid];
      float v = fmaxf(acc, 0.f);
      size_t oidx = ((size_t)n*128 + i)*256 + h*64 + tid;
      ES2[oidx] = v;
      out_ent[oidx] = v;
    }
    __syncthreads();
  }
}

// ---------------- K8: expand entities back to tokens, build LSTM input ----------------
__global__ void k_expand(const float* __restrict__ ES2, const float* __restrict__ emap,
                         const float* __restrict__ doc, float* __restrict__ INP){
  int b = blockIdx.x;       // n*512+l, 4096
  int n = b >> 9, l = b & 511;
  int tid = threadIdx.x;    // 256
  __shared__ float mcol[128];
  if (tid < 128) mcol[tid] = emap[((size_t)n*128 + tid)*512 + l];
  __syncthreads();
  float acc = 0.f;
  const float* e2 = ES2 + (size_t)n*128*256 + tid;
  for (int e = 0; e < 128; e++){
    float m = mcol[e];
    if (m != 0.f) acc += m * e2[(size_t)e*256];   // uniform branch
  }
  float* o = INP + (size_t)b*512;
  o[tid] = acc;
  o[256 + tid] = doc[(size_t)b*256 + tid];
}

// ---------------- K9: input-projection GEMMs via bf16 MFMA ----------------
// Writes GATE-INTERLEAVED layout: G[m][j*4 + q] where original g = q*128 + j.
// This lets k_lstm load all 4 gate pre-acts for unit j as one float4.
__global__ __launch_bounds__(256) void k_gatein(const float* __restrict__ INP,
                         const float* __restrict__ Wf, const float* __restrict__ Wb,
                         const float* __restrict__ bihf, const float* __restrict__ bhhf,
                         const float* __restrict__ bihb, const float* __restrict__ bhhb,
                         float* __restrict__ GF, float* __restrict__ GB){
  int mt = blockIdx.x, gt = blockIdx.y, dir = blockIdx.z;
  const float* W = dir ? Wb : Wf;
  float* Gout = dir ? GB : GF;
  const float* bi = dir ? bihb : bihf;
  const float* bh = dir ? bhhb : bhhf;
  int tid = threadIdx.x;
  int lane = tid & 63, w = tid >> 6;
  int wm = w >> 1, wg = w & 1;
  int m0 = mt*64 + wm*32;
  int g0 = gt*64 + wg*32;
  int lr = lane & 15, lk8 = (lane >> 4) * 8;

  const float* a0p = INP + (size_t)(m0 + lr)*512 + lk8;
  const float* a1p = a0p + (size_t)16*512;
  const float* b0p = W   + (size_t)(g0 + lr)*512 + lk8;
  const float* b1p = b0p + (size_t)16*512;

  f32x4 acc[2][2] = {};
  for (int k0 = 0; k0 < 512; k0 += 32){
    bf16x8 af[2], bfr[2];
    {
      float4 u = *(const float4*)a0p, v = *(const float4*)(a0p + 4);
      bf16x8 r; r[0]=(short)f2bf(u.x); r[1]=(short)f2bf(u.y); r[2]=(short)f2bf(u.z); r[3]=(short)f2bf(u.w);
      r[4]=(short)f2bf(v.x); r[5]=(short)f2bf(v.y); r[6]=(short)f2bf(v.z); r[7]=(short)f2bf(v.w);
      af[0]=r;
    }
    {
      float4 u = *(const float4*)a1p, v = *(const float4*)(a1p + 4);
      bf16x8 r; r[0]=(short)f2bf(u.x); r[1]=(short)f2bf(u.y); r[2]=(short)f2bf(u.z); r[3]=(short)f2bf(u.w);
      r[4]=(short)f2bf(v.x); r[5]=(short)f2bf(v.y); r[6]=(short)f2bf(v.z); r[7]=(short)f2bf(v.w);
      af[1]=r;
    }
    {
      float4 u = *(const float4*)b0p, v = *(const float4*)(b0p + 4);
      bf16x8 r; r[0]=(short)f2bf(u.x); r[1]=(short)f2bf(u.y); r[2]=(short)f2bf(u.z); r[3]=(short)f2bf(u.w);
      r[4]=(short)f2bf(v.x); r[5]=(short)f2bf(v.y); r[6]=(short)f2bf(v.z); r[7]=(short)f2bf(v.w);
      bfr[0]=r;
    }
    {
      float4 u = *(const float4*)b1p, v = *(const float4*)(b1p + 4);
      bf16x8 r; r[0]=(short)f2bf(u.x); r[1]=(short)f2bf(u.y); r[2]=(short)f2bf(u.z); r[3]=(short)f2bf(u.w);
      r[4]=(short)f2bf(v.x); r[5]=(short)f2bf(v.y); r[6]=(short)f2bf(v.z); r[7]=(short)f2bf(v.w);
      bfr[1]=r;
    }
    a0p += 32; a1p += 32; b0p += 32; b1p += 32;
    #pragma unroll
    for (int im = 0; im < 2; im++)
      #pragma unroll
      for (int ig = 0; ig < 2; ig++)
        acc[im][ig] = __builtin_amdgcn_mfma_f32_16x16x32_bf16(af[im], bfr[ig], acc[im][ig], 0, 0, 0);
  }
  // C/D layout: col = lane&15, row = (lane>>4)*4 + reg   [m89 verified]
  int crow = (lane >> 4) * 4;
  int ccol = lane & 15;
  #pragma unroll
  for (int im = 0; im < 2; im++)
    #pragma unroll
    for (int ig = 0; ig < 2; ig++){
      int g = g0 + ig*16 + ccol;
      float bias = bi[g] + bh[g];
      int p = (g & 127)*4 + (g >> 7);   // gate-interleaved position
      #pragma unroll
      for (int r = 0; r < 4; r++){
        int m = m0 + im*16 + crow + r;
        Gout[(size_t)m*512 + p] = acc[im][ig][r] + bias;
      }
    }
}

// ---------------- K10: LSTM recurrence ----------------
// 16 blocks (n x dir) x 256 threads (4 waves), 1 block/CU. launch_bounds
// (256,1) lifts the VGPR cap (wreg alone needs 128) so nothing spills.
// Thread (j = tid>>1, s = tid&1): all 4 gates of unit j over k-slice
// [64s,64s+64) via v_pk_fma_f16; one quad_perm DPP reduce; G loaded as one
// float4 (gate-interleaved layout from k_gatein), prefetch depth 2; 2x
// unrolled step body; one barrier per step.
__global__ __launch_bounds__(256, 1) void k_lstm(const float* __restrict__ GF,
                                              const float* __restrict__ GB,
                                              const float* __restrict__ Whhf,
                                              const float* __restrict__ Whhb,
                                              float* __restrict__ out){
  int b = blockIdx.x;          // 16
  int dir = b >> 3, n = b & 7;
  const float* G = dir ? GB : GF;
  const float* Whh = dir ? Whhb : Whhf;
  int tid = threadIdx.x;       // 256
  int j = tid >> 1;            // unit 0..127
  int s = tid & 1;             // k-slice half

  // weights: rows q*128+j, cols [64s, 64s+64) -> 4 gates x 32 h2
  h2 wreg[4][32];
  #pragma unroll
  for (int q = 0; q < 4; q++){
    const float* wp = Whh + (size_t)(q*128 + j)*128 + 64*s;
    #pragma unroll
    for (int kk = 0; kk < 32; kk++){
      h2 p; p[0] = (_Float16)wp[2*kk]; p[1] = (_Float16)wp[2*kk+1];
      wreg[q][kk] = p;
    }
  }

  __shared__ __align__(16) _Float16 h_l[2][128];
  if (tid < 128) h_l[0][tid] = (_Float16)0.f;

  const float4* Gp = (const float4*)(G + (size_t)n*512*512) + (dir ? (size_t)511*128 : 0) + j;
  const int gstep = dir ? -128 : 128;    // float4 units per t-step
  float* outp = out + (size_t)n*512*256 + (dir ? (size_t)511*256 : 0) + dir*128 + j;
  const int ostep = dir ? -256 : 256;

  float4 g0, g1;
  g0 = *Gp; Gp += gstep;
  g1 = *Gp; Gp += gstep;
  float c = 0.f;
  __syncthreads();

#define LSTM_STEP(RB, GREG)                                                    \
  {                                                                            \
    const uint4* hb = (const uint4*)(&h_l[RB][64*s]);                          \
    uint4 hv[8];                                                               \
    _Pragma("unroll")                                                          \
    for (int r = 0; r < 8; r++) hv[r] = hb[r];                                 \
    float gci = GREG.x, gcf = GREG.y, gcg = GREG.z, gco = GREG.w;              \
    GREG = *Gp; Gp += gstep;                                                   \
    float accf[4];                                                             \
    _Pragma("unroll")                                                          \
    for (int q = 0; q < 4; q++){                                               \
      h2 a0; a0[0]=(_Float16)0.f; a0[1]=(_Float16)0.f; h2 a1 = a0;             \
      _Pragma("unroll")                                                        \
      for (int r = 0; r < 8; r++){                                             \
        a0 += wreg[q][4*r+0] * u2h(hv[r].x);                                   \
        a1 += wreg[q][4*r+1] * u2h(hv[r].y);                                   \
        a0 += wreg[q][4*r+2] * u2h(hv[r].z);                                   \
        a1 += wreg[q][4*r+3] * u2h(hv[r].w);                                   \
      }                                                                        \
      h2 hs = a0 + a1;                                                         \
      accf[q] = (float)hs[0] + (float)hs[1];                                   \
    }                                                                          \
    _Pragma("unroll")                                                          \
    for (int q = 0; q < 4; q++){                                               \
      accf[q] += qperm<0xB1>(accf[q]);                                         \
    }                                                                          \
    float vi = accf[0] + gci, vf = accf[1] + gcf;                              \
    float vg = accf[2] + gcg, vo = accf[3] + gco;                              \
    c = fsigm(vf) * c + fsigm(vi) * ftanh(vg);                                 \
    float hval = fsigm(vo) * ftanh(c);                                         \
    if (s == 0) h_l[RB^1][j] = (_Float16)hval;                                 \
    else        *outp = hval;                                                  \
    outp += ostep;                                                             \
    __syncthreads();                                                           \
  }

  for (int t = 0; t < 512; t += 2){
    LSTM_STEP(0, g0)
    LSTM_STEP(1, g1)
  }
#undef LSTM_STEP
}

extern "C" void kernel_launch(void* const* d_in, const int* in_sizes, int n_in,
                              void* d_out, int out_size, void* d_ws, size_t ws_size,
                              hipStream_t stream){
  const float* doc   = (const float*)d_in[0];
  const float* qvec  = (const float*)d_in[1];
  const float* emap  = (const float*)d_in[3];
  const float* emask = (const float*)d_in[4];
  const float* qw    = (const float*)d_in[5];
  const float* Wt    = (const float*)d_in[6];
  const float* at    = (const float*)d_in[7];
  const float* qa1   = (const float*)d_in[8];
  const float* qa2   = (const float*)d_in[9];
  const float* Wihf  = (const float*)d_in[10];
  const float* Whhf  = (const float*)d_in[11];
  const float* bihf  = (const float*)d_in[12];
  const float* bhhf  = (const float*)d_in[13];
  const float* Wihb  = (const float*)d_in[14];
  const float* Whhb  = (const float*)d_in[15];
  const float* bihb  = (const float*)d_in[16];
  const float* bhhb  = (const float*)d_in[17];
  const int*   adj   = (const int*)d_in[19];

  float* out = (float*)d_out;
  float* out_doc = out;                         // 8*512*256
  float* out_ent = out + 8*512*256;             // 8*128*256
  float* out_sm  = out_ent + 8*128*256;         // 8*128

  float* w = (float*)d_ws;
  float* ES   = w; w += 8*128*512;
  float* AM   = w; w += 8*128;
  float* HALL = w; w += 12*1024*64;
  float* WSRC = w; w += 12*8*64;
  float* WDST = w; w += 12*8*64;
  float* SRC  = w; w += 12*8*128;
  float* DST  = w; w += 12*8*128;
  float* ES2  = w; w += 8*128*256;
  float* INP  = w; w += 8*512*512;
  float* GF   = w; w += 8*512*512;
  float* GB   = w; w += 8*512*512;

  hipLaunchKernelGGL(k_ent_state, dim3(1024), dim3(256), 0, stream, doc, emap, ES);
  hipLaunchKernelGGL(k_qscore,    dim3(8),    dim3(512), 0, stream, qvec, qw, ES, emask, out_sm, AM);
  hipLaunchKernelGGL(k_hall,      dim3(16,12),dim3(256), 0, stream, ES, Wt, HALL);
  hipLaunchKernelGGL(k_qattn,     dim3(12),   dim3(128), 0, stream, qvec, qa1, qa2, at, WSRC, WDST);
  hipLaunchKernelGGL(k_srcdst,    dim3(96),   dim3(128), 0, stream, HALL, WSRC, WDST, SRC, DST);
  hipLaunchKernelGGL(k_attn,      dim3(256),  dim3(128), 0, stream, HALL, SRC, DST, AM, adj, ES2, out_ent);
  hipLaunchKernelGGL(k_expand,    dim3(4096), dim3(256), 0, stream, ES2, emap, doc, INP);
  hipLaunchKernelGGL(k_gatein,    dim3(64,8,2), dim3(256), 0, stream, INP, Wihf, Wihb, bihf, bhhf, bihb, bhhb, GF, GB);
  hipLaunchKernelGGL(k_lstm,      dim3(16),   dim3(256), 0, stream, GF, GB, Whhf, Whhb, out_doc);
}